// Round 1
// 1748.684 us; speedup vs baseline: 1.1777x; 1.1777x over previous
//
#include <hip/hip_runtime.h>
#include <hip/hip_bf16.h>

// B=2, S=2048, HID=4096, NH=32, D=128, G=8, GS=4, RK=256, FGD=256, FH=8192
typedef __hip_bfloat16 bf16;
typedef __bf16 bf16x8 __attribute__((ext_vector_type(8)));
typedef float f32x4 __attribute__((ext_vector_type(4)));

#define MFMA16(a, b, c) __builtin_amdgcn_mfma_f32_16x16x32_bf16(a, b, c, 0, 0, 0)

__device__ __forceinline__ void llds16(const bf16* g, bf16* lds) {
  __builtin_amdgcn_global_load_lds(
      (const __attribute__((address_space(1))) unsigned int*)g,
      (__attribute__((address_space(3))) unsigned int*)lds, 16, 0, 0);
}

__device__ __forceinline__ void storeC(float* p, float v) { *p = v; }
__device__ __forceinline__ void storeC(bf16* p, float v) { *p = __float2bfloat16(v); }

// ---------------- fp32 -> bf16 convert (vectorized) ----------------
__global__ __launch_bounds__(256) void cvt_f2b(const float* __restrict__ in,
                                               bf16* __restrict__ out, int n4) {
  int i = blockIdx.x * 256 + threadIdx.x;
  if (i >= n4) return;
  float4 v = ((const float4*)in)[i];
  union { bf16 h[4]; short4 s; } u;
  u.h[0] = __float2bfloat16(v.x);
  u.h[1] = __float2bfloat16(v.y);
  u.h[2] = __float2bfloat16(v.z);
  u.h[3] = __float2bfloat16(v.w);
  ((short4*)out)[i] = u.s;
}

// ---------------- generic bf16 GEMM: C = A(MxK,lda) . B(NxK,ldb)^T ----------------
template <typename OUT_T>
__global__ __launch_bounds__(256) void gemm_bt(
    const bf16* __restrict__ A, const bf16* __restrict__ B, OUT_T* __restrict__ C,
    int M, int N, int K, int lda, int ldb, int ldc,
    long batchA, long batchB, long batchC) {
  __shared__ alignas(16) bf16 As[128 * 32];
  __shared__ alignas(16) bf16 Bs[128 * 32];
  const int t = threadIdx.x;
  const int w = t >> 6, l = t & 63;
  const int lane_r = l & 15, quad = l >> 4;
  const int wm = (w >> 1) * 64, wn = (w & 1) * 64;
  const long m0 = (long)blockIdx.y * 128, n0 = (long)blockIdx.x * 128;
  A += (long)blockIdx.z * batchA;
  B += (long)blockIdx.z * batchB;
  C += (long)blockIdx.z * batchC;
  const int r0a = t >> 2;
  const int cba = (t & 3) * 8;
  f32x4 acc[4][4] = {};
  for (int k0 = 0; k0 < K; k0 += 32) {
    llds16(A + (m0 + r0a) * lda + k0 + cba, &As[t * 8]);
    llds16(A + (m0 + r0a + 64) * lda + k0 + cba, &As[(t + 256) * 8]);
    llds16(B + (n0 + r0a) * ldb + k0 + cba, &Bs[t * 8]);
    llds16(B + (n0 + r0a + 64) * ldb + k0 + cba, &Bs[(t + 256) * 8]);
    __syncthreads();
    bf16x8 af[4], bfr[4];
#pragma unroll
    for (int mt = 0; mt < 4; ++mt)
      af[mt] = *(const bf16x8*)&As[(wm + mt * 16 + lane_r) * 32 + quad * 8];
#pragma unroll
    for (int nt = 0; nt < 4; ++nt)
      bfr[nt] = *(const bf16x8*)&Bs[(wn + nt * 16 + lane_r) * 32 + quad * 8];
#pragma unroll
    for (int mt = 0; mt < 4; ++mt)
#pragma unroll
      for (int nt = 0; nt < 4; ++nt)
        acc[mt][nt] = MFMA16(af[mt], bfr[nt], acc[mt][nt]);
    __syncthreads();
  }
#pragma unroll
  for (int mt = 0; mt < 4; ++mt)
#pragma unroll
    for (int nt = 0; nt < 4; ++nt) {
      long row = m0 + wm + mt * 16 + quad * 4;
      long col = n0 + wn + nt * 16 + lane_r;
#pragma unroll
      for (int r = 0; r < 4; ++r) storeC(&C[(row + r) * ldc + col], acc[mt][nt][r]);
    }
}

// ------- RoPE + layout permute: (B,S,NH,128) -> (B,NH,S,128), out-of-place -------
__global__ __launch_bounds__(256) void rope_perm(const bf16* __restrict__ in,
                                                 bf16* __restrict__ out,
                                                 const int* __restrict__ pos_ids) {
  int idx = blockIdx.x * 256 + threadIdx.x;  // B*S*NH*64 threads
  int d = idx & 63;
  int h = (idx >> 6) & 31;
  int bs = idx >> 11;
  int b = bs >> 11, s = bs & 2047;
  float pos = (float)pos_ids[bs];
  float inv = exp2f(-(float)d * (13.287712379549449f / 64.0f));
  float fr = pos * inv, sn, cs;
  sincosf(fr, &sn, &cs);
  long bi = (long)bs * 4096 + h * 128 + d;
  long bo = ((long)(b * 32 + h) * 2048 + s) * 128 + d;
  float x1 = __bfloat162float(in[bi]);
  float x2 = __bfloat162float(in[bi + 64]);
  out[bo] = __float2bfloat16(x1 * cs - x2 * sn);
  out[bo + 64] = __float2bfloat16(x2 * cs + x1 * sn);
}

// -------- transpose v_lat (b,s,2048) -> tiled Vt: (b,g,kt) blocks of (256 x 32) ----
__global__ __launch_bounds__(256) void transpose_kernel(const bf16* __restrict__ v,
                                                        bf16* __restrict__ vt) {
  __shared__ bf16 tile[32][33];
  int b = blockIdx.z;
  int c0 = blockIdx.x * 32;  // column in 2048 (= g*256 + d)
  int r0 = blockIdx.y * 32;  // row (s)
  int tx = threadIdx.x & 31, ty = threadIdx.x >> 5;
#pragma unroll
  for (int p = 0; p < 4; ++p) {
    int r = ty + p * 8;
    tile[r][tx] = v[((long)b * 2048 + r0 + r) * 2048 + c0 + tx];
  }
  __syncthreads();
#pragma unroll
  for (int p = 0; p < 4; ++p) {
    int cidx = ty + p * 8;
    int cg = c0 + cidx;          // global column = g*256 + d
    int g = cg >> 8, d = cg & 255;
    int s = r0 + tx;
    vt[((long)((b * 8 + g) * 64 + (s >> 5))) * 8192 + d * 32 + (s & 31)] = tile[tx][cidx];
  }
}

// ---------------- flash attention v4: QBLK=256, KVBLK=32, double-buffered pipeline --
// grid (S/256 reversed, NH, B), 512 threads; wave w owns q rows [q0+32w, +32)
// Q,K: (B,NH,S,128) head-major. Vt: tiled (b,g,kt,256x32). fused: (B,S,8192).
// LDS (bf16 elems): K0 @0 (4096) | K1 @4096 | V0 @8192 (8192) | V1 @16384 | P @24576 (8192)
__global__ __launch_bounds__(512, 2) void attn_kernel(const bf16* __restrict__ Q,
                                                      const bf16* __restrict__ Kg,
                                                      const bf16* __restrict__ Vt,
                                                      bf16* __restrict__ fused) {
  __shared__ alignas(16) bf16 smem[32768];  // 64 KB
  const int t = threadIdx.x, w = t >> 6, l = t & 63;
  const int lane_r = l & 15, quad = l >> 4;
  const int qt = (int)gridDim.x - 1 - (int)blockIdx.x;  // long blocks dispatch first
  const int q0 = qt * 256;
  const int h = blockIdx.y, b = blockIdx.z;
  const int g = h >> 2, j = h & 3;
  const int qr0 = q0 + w * 32;
  const float scale = 0.08838834764831845f;  // 1/sqrt(128)

  // Q fragments: 2 m-tiles x 4 k-chunks (A-operand: m=lane&15, k=quad*8+jj)
  const bf16* qbase = Q + ((long)(b * 32 + h) * 2048 + qr0 + lane_r) * 128 + quad * 8;
  bf16x8 qf[2][4];
#pragma unroll
  for (int m = 0; m < 2; ++m)
#pragma unroll
    for (int kd = 0; kd < 4; ++kd)
      qf[m][kd] = *(const bf16x8*)(qbase + m * 16 * 128 + kd * 32);

  f32x4 acc[2][16] = {};
  float m_i[2][4], l_i[2][4];
#pragma unroll
  for (int m = 0; m < 2; ++m)
#pragma unroll
    for (int r = 0; r < 4; ++r) { m_i[m][r] = -1e30f; l_i[m][r] = 0.f; }

  const bf16* Kbase = Kg + (long)(b * 32 + h) * 2048 * 128;
  const bf16* Vtg = Vt + (long)(b * 8 + g) * 524288;
  const int nk = (q0 >> 5) + 8;
  bf16* Pw = smem + 24576 + w * 1024;  // 32 rows x 32 kv per wave

  // staging geometry: K tile 32x128 (512 chunks, slot s&15 holds chunk (s&15)^(r&15));
  //                   V tile 256x32 (1024 chunks, slot s&3 holds chunk (s&3)^((r>>1)&3))
  const int kr = t >> 4, ck = (t & 15) ^ (kr & 15);
  const int vr0 = t >> 2, cv0 = (t & 3) ^ ((vr0 >> 1) & 3);
  const int vr1 = (t + 512) >> 2, cv1 = ((t + 512) & 3) ^ ((vr1 >> 1) & 3);
  const bf16* ksrc0 = Kbase + (long)kr * 128 + ck * 8;
  const bf16* vsrc0 = Vtg + (long)vr0 * 32 + cv0 * 8;
  const bf16* vsrc1 = Vtg + (long)vr1 * 32 + cv1 * 8;

#define STAGE_T(buf, kt)                                                           \
  do {                                                                             \
    llds16(ksrc0 + (long)(kt) * 4096, &smem[(buf) * 4096 + t * 8]);                \
    llds16(vsrc0 + (long)(kt) * 8192, &smem[8192 + (buf) * 8192 + t * 8]);         \
    llds16(vsrc1 + (long)(kt) * 8192, &smem[8192 + (buf) * 8192 + (t + 512) * 8]); \
  } while (0)

  STAGE_T(0, 0);
  asm volatile("s_waitcnt vmcnt(0)" ::: "memory");
  __builtin_amdgcn_s_barrier();
  __builtin_amdgcn_sched_barrier(0);

  int cur = 0;
  const int pslot = quad ^ ((lane_r >> 1) & 3);
  for (int kt = 0; kt < nk; ++kt) {
    const int k0 = kt * 32;
    if (kt + 1 < nk) STAGE_T(cur ^ 1, kt + 1);  // prefetch overlaps compute below
    const bf16* Ks = &smem[cur * 4096];
    const bf16* Vs = &smem[8192 + cur * 8192];
    if (k0 <= qr0 + 31) {  // wave-uniform: any row of this wave needs this tile
#pragma unroll
      for (int m = 0; m < 2; ++m) {
        if (k0 > qr0 + m * 16 + 15) continue;  // m-tile fully masked
        f32x4 s0 = {}, s1 = {};
#pragma unroll
        for (int kd = 0; kd < 4; ++kd) {
          int csw = (kd * 4 + quad) ^ lane_r;
          bf16x8 kf0 = *(const bf16x8*)&Ks[lane_r * 128 + csw * 8];
          bf16x8 kf1 = *(const bf16x8*)&Ks[(16 + lane_r) * 128 + csw * 8];
          s0 = MFMA16(qf[m][kd], kf0, s0);
          s1 = MFMA16(qf[m][kd], kf1, s1);
        }
        const int qrowb = qr0 + m * 16 + quad * 4;
        float sc[2][4];
#pragma unroll
        for (int r = 0; r < 4; ++r) {
          sc[0][r] = (k0 + lane_r <= qrowb + r) ? s0[r] * scale : -1e30f;
          sc[1][r] = (k0 + 16 + lane_r <= qrowb + r) ? s1[r] * scale : -1e30f;
        }
#pragma unroll
        for (int r = 0; r < 4; ++r) {
          float mx = fmaxf(sc[0][r], sc[1][r]);
#pragma unroll
          for (int o = 1; o < 16; o <<= 1) mx = fmaxf(mx, __shfl_xor(mx, o));
          float mnew = fmaxf(m_i[m][r], mx);
          float alpha = __expf(m_i[m][r] - mnew);
          float p0 = __expf(sc[0][r] - mnew);
          float p1 = __expf(sc[1][r] - mnew);
          sc[0][r] = p0;
          sc[1][r] = p1;
          float rs = p0 + p1;
#pragma unroll
          for (int o = 1; o < 16; o <<= 1) rs += __shfl_xor(rs, o);
          l_i[m][r] = l_i[m][r] * alpha + rs;
          m_i[m][r] = mnew;
#pragma unroll
          for (int nt = 0; nt < 16; ++nt) acc[m][nt][r] *= alpha;
        }
        // P -> LDS (swizzled, wave-private)
#pragma unroll
        for (int ks = 0; ks < 2; ++ks)
#pragma unroll
          for (int r = 0; r < 4; ++r) {
            int row = m * 16 + quad * 4 + r;
            int col = ks * 16 + lane_r;
            int slot = (col >> 3) ^ ((row >> 1) & 3);
            Pw[row * 32 + slot * 8 + (col & 7)] = __float2bfloat16(sc[ks][r]);
          }
      }
      // PV: A=P(16x32 per m), B=V(16 fgd x 32 kv per nt), shared vf across m
      const bool a0 = (k0 <= qr0 + 15);
      bf16x8 pf0, pf1;
      if (a0) pf0 = *(const bf16x8*)&Pw[lane_r * 32 + pslot * 8];
      pf1 = *(const bf16x8*)&Pw[(16 + lane_r) * 32 + pslot * 8];
      __builtin_amdgcn_s_setprio(1);
#pragma unroll
      for (int nt = 0; nt < 16; ++nt) {
        bf16x8 vf = *(const bf16x8*)&Vs[(nt * 16 + lane_r) * 32 + pslot * 8];
        if (a0) acc[0][nt] = MFMA16(pf0, vf, acc[0][nt]);
        acc[1][nt] = MFMA16(pf1, vf, acc[1][nt]);
      }
      __builtin_amdgcn_s_setprio(0);
    }
    // drain this iter's prefetch (issued ~compute-time ago), then cross-wave sync
    asm volatile("s_waitcnt vmcnt(0)" ::: "memory");
    __builtin_amdgcn_s_barrier();
    __builtin_amdgcn_sched_barrier(0);
    cur ^= 1;
  }

  // ---- epilogue: normalize, stage 16x256 per wave in LDS, coalesced 16B stores ----
  __syncthreads();  // all waves done reading K/V/P before smem reuse
  bf16* EP = smem + w * 4096;  // 16 rows x 256 cols per wave (reused per m)
#pragma unroll
  for (int m = 0; m < 2; ++m) {
#pragma unroll
    for (int r = 0; r < 4; ++r) {
      float inv = 1.0f / l_i[m][r];
#pragma unroll
      for (int nt = 0; nt < 16; ++nt)
        EP[(quad * 4 + r) * 256 + nt * 16 + lane_r] = __float2bfloat16(acc[m][nt][r] * inv);
    }
    // wave-private region: per-wave LDS ordering handled by compiler lgkmcnt
#pragma unroll
    for (int op = 0; op < 8; ++op) {
      int row = op * 2 + (l >> 5);
      int qrow = qr0 + m * 16 + row;
      int sOut = j * 512 + (qrow >> 2), fi = qrow & 3;
      bf16x8 vread = *(const bf16x8*)&EP[row * 256 + (l & 31) * 8];
      *(bf16x8*)(fused + ((long)(b * 2048 + sOut)) * 8192 + fi * 2048 + g * 256 +
                 (l & 31) * 8) = vread;
    }
  }
}
#undef STAGE_T

// ---------------- launch ----------------
extern "C" void kernel_launch(void* const* d_in, const int* in_sizes, int n_in,
                              void* d_out, int out_size, void* d_ws, size_t ws_size,
                              hipStream_t stream) {
  const float* hidden = (const float*)d_in[0];
  const int* pos_ids = (const int*)d_in[2];
  const float* Wq = (const float*)d_in[3];
  const float* WVT = (const float*)d_in[4];
  const float* U = (const float*)d_in[5];
  const float* Wv = (const float*)d_in[6];
  const float* Wo = (const float*)d_in[7];
  float* out = (float*)d_out;

  bf16* ws = (bf16*)d_ws;
  bf16* WB = ws;                    // 33554432 (reused for Wq/WVT/Wv/Wo)
  bf16* UB = WB + 33554432;         // 1048576
  bf16* hidB = UB + 1048576;        // 16777216  (later reused as Qh)
  bf16* Qb = hidB + 16777216;       // 16777216
  bf16* Kb = Qb + 16777216;         // 16777216
  bf16* klatB = Kb + 16777216;      // 8388608   (klatB+vlatB later reused as Kh)
  bf16* vlatB = klatB + 8388608;    // 8388608
  bf16* vtB = vlatB + 8388608;      // 8388608   (tiled Vt)
  bf16* fusedB = vtB + 8388608;     // 33554432
  bf16* Qh = hidB;
  bf16* Kh = klatB;

  cvt_f2b<<<16384, 256, 0, stream>>>(hidden, hidB, 16777216 / 4);
  cvt_f2b<<<16384, 256, 0, stream>>>(Wq, WB, 16777216 / 4);
  gemm_bt<bf16><<<dim3(32, 32, 1), 256, 0, stream>>>(hidB, WB, Qb, 4096, 4096, 4096,
                                                     4096, 4096, 4096, 0, 0, 0);
  cvt_f2b<<<8192, 256, 0, stream>>>(WVT, WB, 8388608 / 4);
  gemm_bt<bf16><<<dim3(16, 32, 1), 256, 0, stream>>>(hidB, WB, klatB, 4096, 2048, 4096,
                                                     4096, 4096, 2048, 0, 0, 0);
  cvt_f2b<<<8192, 256, 0, stream>>>(Wv, WB, 8388608 / 4);
  gemm_bt<bf16><<<dim3(16, 32, 1), 256, 0, stream>>>(hidB, WB, vlatB, 4096, 2048, 4096,
                                                     4096, 4096, 2048, 0, 0, 0);
  cvt_f2b<<<1024, 256, 0, stream>>>(U, UB, 1048576 / 4);
  gemm_bt<bf16><<<dim3(4, 32, 8), 256, 0, stream>>>(klatB, UB, Kb, 4096, 512, 256,
                                                    2048, 2048, 4096, 256, 256, 512);
  transpose_kernel<<<dim3(64, 64, 2), 256, 0, stream>>>(vlatB, vtB);  // before Kh reuse
  rope_perm<<<32768, 256, 0, stream>>>(Qb, Qh, pos_ids);
  rope_perm<<<32768, 256, 0, stream>>>(Kb, Kh, pos_ids);
  cvt_f2b<<<32768, 256, 0, stream>>>(Wo, WB, 33554432 / 4);
  attn_kernel<<<dim3(8, 32, 2), 512, 0, stream>>>(Qh, Kh, vtB, fusedB);
  gemm_bt<float><<<dim3(32, 32, 1), 256, 0, stream>>>(fusedB, WB, out, 4096, 4096, 8192,
                                                      8192, 8192, 4096, 0, 0, 0);
}

// Round 2
// 1656.492 us; speedup vs baseline: 1.2432x; 1.0557x over previous
//
#include <hip/hip_runtime.h>
#include <hip/hip_bf16.h>

// B=2, S=2048, HID=4096, NH=32, D=128, G=8, GS=4, RK=256, FGD=256, FH=8192
typedef __hip_bfloat16 bf16;
typedef __bf16 bf16x8 __attribute__((ext_vector_type(8)));
typedef float f32x4 __attribute__((ext_vector_type(4)));

#define MFMA16(a, b, c) __builtin_amdgcn_mfma_f32_16x16x32_bf16(a, b, c, 0, 0, 0)

__device__ __forceinline__ void llds16(const bf16* g, bf16* lds) {
  __builtin_amdgcn_global_load_lds(
      (const __attribute__((address_space(1))) unsigned int*)g,
      (__attribute__((address_space(3))) unsigned int*)lds, 16, 0, 0);
}

__device__ __forceinline__ void storeC(float* p, float v) { *p = v; }
__device__ __forceinline__ void storeC(bf16* p, float v) { *p = __float2bfloat16(v); }

// ---------------- fp32 -> bf16 convert (vectorized) ----------------
__global__ __launch_bounds__(256) void cvt_f2b(const float* __restrict__ in,
                                               bf16* __restrict__ out, int n4) {
  int i = blockIdx.x * 256 + threadIdx.x;
  if (i >= n4) return;
  float4 v = ((const float4*)in)[i];
  union { bf16 h[4]; short4 s; } u;
  u.h[0] = __float2bfloat16(v.x);
  u.h[1] = __float2bfloat16(v.y);
  u.h[2] = __float2bfloat16(v.z);
  u.h[3] = __float2bfloat16(v.w);
  ((short4*)out)[i] = u.s;
}

// ---------------- generic bf16 GEMM: C = A(MxK,lda) . B(NxK,ldb)^T ----------------
template <typename OUT_T>
__global__ __launch_bounds__(256) void gemm_bt(
    const bf16* __restrict__ A, const bf16* __restrict__ B, OUT_T* __restrict__ C,
    int M, int N, int K, int lda, int ldb, int ldc,
    long batchA, long batchB, long batchC) {
  __shared__ alignas(16) bf16 As[128 * 32];
  __shared__ alignas(16) bf16 Bs[128 * 32];
  const int t = threadIdx.x;
  const int w = t >> 6, l = t & 63;
  const int lane_r = l & 15, quad = l >> 4;
  const int wm = (w >> 1) * 64, wn = (w & 1) * 64;
  const long m0 = (long)blockIdx.y * 128, n0 = (long)blockIdx.x * 128;
  A += (long)blockIdx.z * batchA;
  B += (long)blockIdx.z * batchB;
  C += (long)blockIdx.z * batchC;
  const int r0a = t >> 2;
  const int cba = (t & 3) * 8;
  f32x4 acc[4][4] = {};
  for (int k0 = 0; k0 < K; k0 += 32) {
    llds16(A + (m0 + r0a) * lda + k0 + cba, &As[t * 8]);
    llds16(A + (m0 + r0a + 64) * lda + k0 + cba, &As[(t + 256) * 8]);
    llds16(B + (n0 + r0a) * ldb + k0 + cba, &Bs[t * 8]);
    llds16(B + (n0 + r0a + 64) * ldb + k0 + cba, &Bs[(t + 256) * 8]);
    __syncthreads();
    bf16x8 af[4], bfr[4];
#pragma unroll
    for (int mt = 0; mt < 4; ++mt)
      af[mt] = *(const bf16x8*)&As[(wm + mt * 16 + lane_r) * 32 + quad * 8];
#pragma unroll
    for (int nt = 0; nt < 4; ++nt)
      bfr[nt] = *(const bf16x8*)&Bs[(wn + nt * 16 + lane_r) * 32 + quad * 8];
#pragma unroll
    for (int mt = 0; mt < 4; ++mt)
#pragma unroll
      for (int nt = 0; nt < 4; ++nt)
        acc[mt][nt] = MFMA16(af[mt], bfr[nt], acc[mt][nt]);
    __syncthreads();
  }
#pragma unroll
  for (int mt = 0; mt < 4; ++mt)
#pragma unroll
    for (int nt = 0; nt < 4; ++nt) {
      long row = m0 + wm + mt * 16 + quad * 4;
      long col = n0 + wn + nt * 16 + lane_r;
#pragma unroll
      for (int r = 0; r < 4; ++r) storeC(&C[(row + r) * ldc + col], acc[mt][nt][r]);
    }
}

// ------- RoPE + layout permute: (B,S,NH,128) -> (B,NH,S,128), out-of-place -------
__global__ __launch_bounds__(256) void rope_perm(const bf16* __restrict__ in,
                                                 bf16* __restrict__ out,
                                                 const int* __restrict__ pos_ids) {
  int idx = blockIdx.x * 256 + threadIdx.x;  // B*S*NH*64 threads
  int d = idx & 63;
  int h = (idx >> 6) & 31;
  int bs = idx >> 11;
  int b = bs >> 11, s = bs & 2047;
  float pos = (float)pos_ids[bs];
  float inv = exp2f(-(float)d * (13.287712379549449f / 64.0f));
  float fr = pos * inv, sn, cs;
  sincosf(fr, &sn, &cs);
  long bi = (long)bs * 4096 + h * 128 + d;
  long bo = ((long)(b * 32 + h) * 2048 + s) * 128 + d;
  float x1 = __bfloat162float(in[bi]);
  float x2 = __bfloat162float(in[bi + 64]);
  out[bo] = __float2bfloat16(x1 * cs - x2 * sn);
  out[bo + 64] = __float2bfloat16(x2 * cs + x1 * sn);
}

// -------- transpose v_lat (b,s,2048) -> tiled Vt: (b,g,kt) blocks of (256 x 32) ----
__global__ __launch_bounds__(256) void transpose_kernel(const bf16* __restrict__ v,
                                                        bf16* __restrict__ vt) {
  __shared__ bf16 tile[32][33];
  int b = blockIdx.z;
  int c0 = blockIdx.x * 32;  // column in 2048 (= g*256 + d)
  int r0 = blockIdx.y * 32;  // row (s)
  int tx = threadIdx.x & 31, ty = threadIdx.x >> 5;
#pragma unroll
  for (int p = 0; p < 4; ++p) {
    int r = ty + p * 8;
    tile[r][tx] = v[((long)b * 2048 + r0 + r) * 2048 + c0 + tx];
  }
  __syncthreads();
#pragma unroll
  for (int p = 0; p < 4; ++p) {
    int cidx = ty + p * 8;
    int cg = c0 + cidx;          // global column = g*256 + d
    int g = cg >> 8, d = cg & 255;
    int s = r0 + tx;
    vt[((long)((b * 8 + g) * 64 + (s >> 5))) * 8192 + d * 32 + (s & 31)] = tile[tx][cidx];
  }
}

// ---------------- flash attention v5: barrier-free, direct L2/L3 streaming --------
// 1-D grid of 512 blocks, balanced pairing: L<256 -> qt{7..4}, L>=256 -> qt{0..3}.
// 512 threads; wave w owns q rows [qt*256+32w, +32) and loops over exactly the
// KV tiles it needs (KVBLK=32), reading K/V fragments straight from global
// (L2/L3-resident: round-1 FETCH showed 127 MB). No in-loop barriers.
// Q,K: (B,NH,S,128) head-major. Vt: tiled (b,g,kt,256x32). fused: (B,S,8192).
__global__ __launch_bounds__(512, 2) void attn_kernel(const bf16* __restrict__ Q,
                                                      const bf16* __restrict__ Kg,
                                                      const bf16* __restrict__ Vt,
                                                      bf16* __restrict__ fused) {
  __shared__ alignas(16) bf16 smem[32768];  // P: w*1024 (first 16KB); EP: w*4096 (all 64KB)
  const int t = threadIdx.x, w = t >> 6, l = t & 63;
  const int lane_r = l & 15, quad = l >> 4;
  // balanced 1-D decode: CU pairs sum to constant work (long blocks first)
  const int L = blockIdx.x;
  const int half = L >> 8, pair = L & 255;
  const int hb = pair >> 2, slot = pair & 3;
  const int qt = half ? slot : (7 - slot);
  const int b = hb >> 5, h = hb & 31;
  const int g = h >> 2, j = h & 3;
  const int q0 = qt * 256;
  const int qr0 = q0 + w * 32;
  const float scale = 0.08838834764831845f;  // 1/sqrt(128)

  // Q fragments: 2 m-tiles x 4 k-chunks (A-operand: m=lane&15, k=quad*8+jj)
  const bf16* qbase = Q + ((long)(b * 32 + h) * 2048 + qr0 + lane_r) * 128 + quad * 8;
  bf16x8 qf[2][4];
#pragma unroll
  for (int m = 0; m < 2; ++m)
#pragma unroll
    for (int kd = 0; kd < 4; ++kd)
      qf[m][kd] = *(const bf16x8*)(qbase + m * 2048 + kd * 32);

  f32x4 acc[2][16] = {};
  float m_i[2][4], l_i[2][4];
#pragma unroll
  for (int m = 0; m < 2; ++m)
#pragma unroll
    for (int r = 0; r < 4; ++r) { m_i[m][r] = -1e30f; l_i[m][r] = 0.f; }

  // per-lane fragment bases (direct global reads)
  const bf16* Kf = Kg + (long)(b * 32 + h) * 262144 + lane_r * 128 + quad * 8;
  const bf16* Vf = Vt + (long)(b * 8 + g) * 524288 + lane_r * 32 + quad * 8;
  bf16* Pw = smem + w * 1024;  // 32 rows x 32 cols, wave-private
  const int pslot = quad ^ ((lane_r >> 1) & 3);
  // precomputed swizzled P-store offsets (per r; add m*512 at use)
  int poff0[4], poff1[4];
  {
    const int hi = lane_r >> 3, lo = lane_r & 7;
#pragma unroll
    for (int r = 0; r < 4; ++r) {
      int rq = quad * 4 + r;
      int sw = (rq >> 1) & 3;
      poff0[r] = rq * 32 + ((hi ^ sw) << 3) + lo;
      poff1[r] = rq * 32 + (((2 + hi) ^ sw) << 3) + lo;
    }
  }

  const int nkw = (qr0 >> 5) + 1;  // wave-private tile count (last tile = diagonal)
  for (int kt = 0; kt < nkw; ++kt) {
    const int k0 = kt * 32;
    const bool diag = (kt == nkw - 1);
    const bf16* Kt_ = Kf + (long)k0 * 128;
    const bf16* Vt_ = Vf + (long)kt * 8192;

    // ---- QK^T: K fragments straight from global (16B/lane, 64B row segments) ----
    f32x4 s[2][2] = {};
#pragma unroll
    for (int ks = 0; ks < 2; ++ks) {
      bf16x8 kf[4];
#pragma unroll
      for (int kd = 0; kd < 4; ++kd)
        kf[kd] = *(const bf16x8*)(Kt_ + ks * 2048 + kd * 32);
#pragma unroll
      for (int kd = 0; kd < 4; ++kd) {
        s[0][ks] = MFMA16(qf[0][kd], kf[kd], s[0][ks]);
        s[1][ks] = MFMA16(qf[1][kd], kf[kd], s[1][ks]);
      }
    }
    // scale (+ causal mask only on the wave's own diagonal tile)
    float sc[2][2][4];
    if (diag) {
#pragma unroll
      for (int m = 0; m < 2; ++m) {
        const int qrowb = qr0 + m * 16 + quad * 4;
#pragma unroll
        for (int r = 0; r < 4; ++r) {
          sc[m][0][r] = (k0 + lane_r <= qrowb + r) ? s[m][0][r] * scale : -1e30f;
          sc[m][1][r] = (k0 + 16 + lane_r <= qrowb + r) ? s[m][1][r] * scale : -1e30f;
        }
      }
    } else {
#pragma unroll
      for (int m = 0; m < 2; ++m)
#pragma unroll
        for (int r = 0; r < 4; ++r) {
          sc[m][0][r] = s[m][0][r] * scale;
          sc[m][1][r] = s[m][1][r] * scale;
        }
    }

    // ---- online softmax (defer-rescale: skip acc pass when no row max grew) ----
#pragma unroll
    for (int m = 0; m < 2; ++m) {
      float mx[4];
      bool grow = false;
#pragma unroll
      for (int r = 0; r < 4; ++r) {
        float v = fmaxf(sc[m][0][r], sc[m][1][r]);
#pragma unroll
        for (int o = 1; o < 16; o <<= 1) v = fmaxf(v, __shfl_xor(v, o));
        mx[r] = v;
        grow = grow || (v > m_i[m][r]);
      }
      if (__any((int)grow)) {
#pragma unroll
        for (int r = 0; r < 4; ++r) {
          float mnew = fmaxf(m_i[m][r], mx[r]);
          float alpha = __expf(m_i[m][r] - mnew);
          m_i[m][r] = mnew;
          l_i[m][r] *= alpha;
#pragma unroll
          for (int nt = 0; nt < 16; ++nt) acc[m][nt][r] *= alpha;
        }
      }
#pragma unroll
      for (int r = 0; r < 4; ++r) {
        float p0 = __expf(sc[m][0][r] - m_i[m][r]);
        float p1 = __expf(sc[m][1][r] - m_i[m][r]);
        float rs = p0 + p1;
#pragma unroll
        for (int o = 1; o < 16; o <<= 1) rs += __shfl_xor(rs, o);
        l_i[m][r] += rs;
        Pw[m * 512 + poff0[r]] = __float2bfloat16(p0);
        Pw[m * 512 + poff1[r]] = __float2bfloat16(p1);
      }
    }

    // ---- PV: P from wave-private LDS, V fragments straight from global ----
    bf16x8 pf0 = *(const bf16x8*)&Pw[lane_r * 32 + pslot * 8];
    bf16x8 pf1 = *(const bf16x8*)&Pw[(16 + lane_r) * 32 + pslot * 8];
    __builtin_amdgcn_s_setprio(1);
#pragma unroll
    for (int nt = 0; nt < 16; ++nt) {
      bf16x8 vf = *(const bf16x8*)(Vt_ + nt * 512);
      acc[0][nt] = MFMA16(pf0, vf, acc[0][nt]);
      acc[1][nt] = MFMA16(pf1, vf, acc[1][nt]);
    }
    __builtin_amdgcn_s_setprio(0);
  }

  // ---- epilogue: normalize, stage 16x256 per wave in LDS, coalesced 16B stores ----
  __syncthreads();  // all waves done with P before smem reuse
  bf16* EP = smem + w * 4096;  // 16 rows x 256 cols per wave (reused per m)
#pragma unroll
  for (int m = 0; m < 2; ++m) {
#pragma unroll
    for (int r = 0; r < 4; ++r) {
      float inv = 1.0f / l_i[m][r];
#pragma unroll
      for (int nt = 0; nt < 16; ++nt)
        EP[(quad * 4 + r) * 256 + nt * 16 + lane_r] = __float2bfloat16(acc[m][nt][r] * inv);
    }
#pragma unroll
    for (int op = 0; op < 8; ++op) {
      int row = op * 2 + (l >> 5);
      int qrow = qr0 + m * 16 + row;
      int sOut = j * 512 + (qrow >> 2), fi = qrow & 3;
      bf16x8 vread = *(const bf16x8*)&EP[row * 256 + (l & 31) * 8];
      *(bf16x8*)(fused + ((long)(b * 2048 + sOut)) * 8192 + fi * 2048 + g * 256 +
                 (l & 31) * 8) = vread;
    }
  }
}

// ---------------- launch ----------------
extern "C" void kernel_launch(void* const* d_in, const int* in_sizes, int n_in,
                              void* d_out, int out_size, void* d_ws, size_t ws_size,
                              hipStream_t stream) {
  const float* hidden = (const float*)d_in[0];
  const int* pos_ids = (const int*)d_in[2];
  const float* Wq = (const float*)d_in[3];
  const float* WVT = (const float*)d_in[4];
  const float* U = (const float*)d_in[5];
  const float* Wv = (const float*)d_in[6];
  const float* Wo = (const float*)d_in[7];
  float* out = (float*)d_out;

  bf16* ws = (bf16*)d_ws;
  bf16* WB = ws;                    // 33554432 (reused for Wq/WVT/Wv/Wo)
  bf16* UB = WB + 33554432;         // 1048576
  bf16* hidB = UB + 1048576;        // 16777216  (later reused as Qh)
  bf16* Qb = hidB + 16777216;       // 16777216
  bf16* Kb = Qb + 16777216;         // 16777216
  bf16* klatB = Kb + 16777216;      // 8388608   (klatB+vlatB later reused as Kh)
  bf16* vlatB = klatB + 8388608;    // 8388608
  bf16* vtB = vlatB + 8388608;      // 8388608   (tiled Vt)
  bf16* fusedB = vtB + 8388608;     // 33554432
  bf16* Qh = hidB;
  bf16* Kh = klatB;

  cvt_f2b<<<16384, 256, 0, stream>>>(hidden, hidB, 16777216 / 4);
  cvt_f2b<<<16384, 256, 0, stream>>>(Wq, WB, 16777216 / 4);
  gemm_bt<bf16><<<dim3(32, 32, 1), 256, 0, stream>>>(hidB, WB, Qb, 4096, 4096, 4096,
                                                     4096, 4096, 4096, 0, 0, 0);
  cvt_f2b<<<8192, 256, 0, stream>>>(WVT, WB, 8388608 / 4);
  gemm_bt<bf16><<<dim3(16, 32, 1), 256, 0, stream>>>(hidB, WB, klatB, 4096, 2048, 4096,
                                                     4096, 4096, 2048, 0, 0, 0);
  cvt_f2b<<<8192, 256, 0, stream>>>(Wv, WB, 8388608 / 4);
  gemm_bt<bf16><<<dim3(16, 32, 1), 256, 0, stream>>>(hidB, WB, vlatB, 4096, 2048, 4096,
                                                     4096, 4096, 2048, 0, 0, 0);
  cvt_f2b<<<1024, 256, 0, stream>>>(U, UB, 1048576 / 4);
  gemm_bt<bf16><<<dim3(4, 32, 8), 256, 0, stream>>>(klatB, UB, Kb, 4096, 512, 256,
                                                    2048, 2048, 4096, 256, 256, 512);
  transpose_kernel<<<dim3(64, 64, 2), 256, 0, stream>>>(vlatB, vtB);  // before Kh reuse
  rope_perm<<<32768, 256, 0, stream>>>(Qb, Qh, pos_ids);
  rope_perm<<<32768, 256, 0, stream>>>(Kb, Kh, pos_ids);
  cvt_f2b<<<32768, 256, 0, stream>>>(Wo, WB, 33554432 / 4);
  attn_kernel<<<dim3(512, 1, 1), 512, 0, stream>>>(Qh, Kh, vtB, fusedB);
  gemm_bt<float><<<dim3(32, 32, 1), 256, 0, stream>>>(fusedB, WB, out, 4096, 4096, 8192,
                                                      8192, 8192, 4096, 0, 0, 0);
}

// Round 3
// 1382.810 us; speedup vs baseline: 1.4893x; 1.1979x over previous
//
#include <hip/hip_runtime.h>
#include <hip/hip_bf16.h>

// B=2, S=2048, HID=4096, NH=32, D=128, G=8, GS=4, RK=256, FGD=256, FH=8192
typedef __hip_bfloat16 bf16;
typedef __bf16 bf16x8 __attribute__((ext_vector_type(8)));
typedef float f32x4 __attribute__((ext_vector_type(4)));

#define MFMA16(a, b, c) __builtin_amdgcn_mfma_f32_16x16x32_bf16(a, b, c, 0, 0, 0)

__device__ __forceinline__ void llds16(const bf16* g, bf16* lds) {
  __builtin_amdgcn_global_load_lds(
      (const __attribute__((address_space(1))) unsigned int*)g,
      (__attribute__((address_space(3))) unsigned int*)lds, 16, 0, 0);
}

__device__ __forceinline__ void storeC(float* p, float v) { *p = v; }
__device__ __forceinline__ void storeC(bf16* p, float v) { *p = __float2bfloat16(v); }

// ---------------- fp32 -> bf16 convert (vectorized) ----------------
__global__ __launch_bounds__(256) void cvt_f2b(const float* __restrict__ in,
                                               bf16* __restrict__ out, int n4) {
  int i = blockIdx.x * 256 + threadIdx.x;
  if (i >= n4) return;
  float4 v = ((const float4*)in)[i];
  union { bf16 h[4]; short4 s; } u;
  u.h[0] = __float2bfloat16(v.x);
  u.h[1] = __float2bfloat16(v.y);
  u.h[2] = __float2bfloat16(v.z);
  u.h[3] = __float2bfloat16(v.w);
  ((short4*)out)[i] = u.s;
}

// ------- 256x256-tile pipelined bf16 GEMM: C = A(MxK,lda) . B(NxK,ldb)^T ----------
// 512 threads = 8 waves (2M x 4N), per-wave 128x64 output. BK=32.
// 3-slot LDS ring (96 KB dynamic), staged 2 K-tiles ahead via global_load_lds;
// steady-state s_waitcnt vmcnt(8) (never drains in-loop). Chunk-XOR swizzle
// (slot = chunk ^ (row&3)) applied on stage-SOURCE and read (both-sides rule).
// Requires M%256==0, N%256==0, K%32==0, K>=96.
template <typename OUT_T>
__global__ __launch_bounds__(512, 2) void gemm256(
    const bf16* __restrict__ A, const bf16* __restrict__ B, OUT_T* __restrict__ C,
    int K, int lda, int ldb, int ldc) {
  extern __shared__ bf16 sm[];  // 3 slots x (A 8192 + B 8192) elems
  const int t = threadIdx.x, w = t >> 6, l = t & 63;
  const int lane_r = l & 15, quad = l >> 4;
  const int wm = (w >> 2) * 128, wn = (w & 3) * 64;
  const long m0 = (long)blockIdx.y * 256, n0 = (long)blockIdx.x * 256;
  // staging: thread t owns chunk indices {t, t+512} of each 2048-chunk tile.
  // chunk s -> row s>>2, slot s&3, which must CONTAIN logical chunk (s&3)^(row&3).
  const int r0 = t >> 2;
  const int c0 = (((t & 3) ^ (r0 & 3)) << 3);  // (t+512): row+128, same swizzled col
  const bf16* As0 = A + (m0 + r0) * lda + c0;
  const bf16* As1 = A + (m0 + r0 + 128) * lda + c0;
  const bf16* Bs0 = B + (n0 + r0) * ldb + c0;
  const bf16* Bs1 = B + (n0 + r0 + 128) * ldb + c0;

#define STAGE(sl, kt)                                   \
  do {                                                  \
    long ko = (long)(kt) * 32;                          \
    bf16* dA = sm + (sl) * 16384;                       \
    bf16* dB = dA + 8192;                               \
    llds16(As0 + ko, dA + t * 8);                       \
    llds16(As1 + ko, dA + (t + 512) * 8);               \
    llds16(Bs0 + ko, dB + t * 8);                       \
    llds16(Bs1 + ko, dB + (t + 512) * 8);               \
  } while (0)

  f32x4 acc[8][4] = {};  // 128 VGPRs
  const int KT = K >> 5;
  const int sw = quad ^ (lane_r & 3);  // lane-constant read slot (row&3 == lane_r&3)

  STAGE(0, 0);
  STAGE(1, 1);
  int sl = 0;
  for (int kt = 0; kt < KT; ++kt) {
    const int pre = KT - 1 - kt;
    if (pre >= 2) {
      int sl2 = sl + 2;
      if (sl2 >= 3) sl2 -= 3;
      STAGE(sl2, kt + 2);
      asm volatile("s_waitcnt vmcnt(8)" ::: "memory");
    } else if (pre == 1) {
      asm volatile("s_waitcnt vmcnt(4)" ::: "memory");
    } else {
      asm volatile("s_waitcnt vmcnt(0)" ::: "memory");
    }
    __builtin_amdgcn_s_barrier();
    __builtin_amdgcn_sched_barrier(0);
    const bf16* Al = sm + sl * 16384;
    const bf16* Bl = Al + 8192;
    bf16x8 af[8], bfr[4];
#pragma unroll
    for (int mt = 0; mt < 8; ++mt)
      af[mt] = *(const bf16x8*)&Al[(wm + mt * 16 + lane_r) * 32 + sw * 8];
#pragma unroll
    for (int nt = 0; nt < 4; ++nt)
      bfr[nt] = *(const bf16x8*)&Bl[(wn + nt * 16 + lane_r) * 32 + sw * 8];
    __builtin_amdgcn_s_setprio(1);
#pragma unroll
    for (int mt = 0; mt < 8; ++mt)
#pragma unroll
      for (int nt = 0; nt < 4; ++nt)
        acc[mt][nt] = MFMA16(af[mt], bfr[nt], acc[mt][nt]);
    __builtin_amdgcn_s_setprio(0);
    __builtin_amdgcn_s_barrier();  // readers done before next iter's STAGE overwrite
    if (++sl == 3) sl = 0;
  }
#undef STAGE

#pragma unroll
  for (int mt = 0; mt < 8; ++mt)
#pragma unroll
    for (int nt = 0; nt < 4; ++nt) {
      long row = m0 + wm + mt * 16 + quad * 4;
      long col = n0 + wn + nt * 16 + lane_r;
#pragma unroll
      for (int r = 0; r < 4; ++r) storeC(&C[(row + r) * ldc + col], acc[mt][nt][r]);
    }
}

// ---------------- generic bf16 GEMM: C = A(MxK,lda) . B(NxK,ldb)^T ----------------
template <typename OUT_T>
__global__ __launch_bounds__(256) void gemm_bt(
    const bf16* __restrict__ A, const bf16* __restrict__ B, OUT_T* __restrict__ C,
    int M, int N, int K, int lda, int ldb, int ldc,
    long batchA, long batchB, long batchC) {
  __shared__ alignas(16) bf16 As[128 * 32];
  __shared__ alignas(16) bf16 Bs[128 * 32];
  const int t = threadIdx.x;
  const int w = t >> 6, l = t & 63;
  const int lane_r = l & 15, quad = l >> 4;
  const int wm = (w >> 1) * 64, wn = (w & 1) * 64;
  const long m0 = (long)blockIdx.y * 128, n0 = (long)blockIdx.x * 128;
  A += (long)blockIdx.z * batchA;
  B += (long)blockIdx.z * batchB;
  C += (long)blockIdx.z * batchC;
  const int r0a = t >> 2;
  const int cba = (t & 3) * 8;
  f32x4 acc[4][4] = {};
  for (int k0 = 0; k0 < K; k0 += 32) {
    llds16(A + (m0 + r0a) * lda + k0 + cba, &As[t * 8]);
    llds16(A + (m0 + r0a + 64) * lda + k0 + cba, &As[(t + 256) * 8]);
    llds16(B + (n0 + r0a) * ldb + k0 + cba, &Bs[t * 8]);
    llds16(B + (n0 + r0a + 64) * ldb + k0 + cba, &Bs[(t + 256) * 8]);
    __syncthreads();
    bf16x8 af[4], bfr[4];
#pragma unroll
    for (int mt = 0; mt < 4; ++mt)
      af[mt] = *(const bf16x8*)&As[(wm + mt * 16 + lane_r) * 32 + quad * 8];
#pragma unroll
    for (int nt = 0; nt < 4; ++nt)
      bfr[nt] = *(const bf16x8*)&Bs[(wn + nt * 16 + lane_r) * 32 + quad * 8];
#pragma unroll
    for (int mt = 0; mt < 4; ++mt)
#pragma unroll
      for (int nt = 0; nt < 4; ++nt)
        acc[mt][nt] = MFMA16(af[mt], bfr[nt], acc[mt][nt]);
    __syncthreads();
  }
#pragma unroll
  for (int mt = 0; mt < 4; ++mt)
#pragma unroll
    for (int nt = 0; nt < 4; ++nt) {
      long row = m0 + wm + mt * 16 + quad * 4;
      long col = n0 + wn + nt * 16 + lane_r;
#pragma unroll
      for (int r = 0; r < 4; ++r) storeC(&C[(row + r) * ldc + col], acc[mt][nt][r]);
    }
}

// ------- RoPE + layout permute: (B,S,NH*128 @ldin) -> (B,NH,S,128), out-of-place ---
__global__ __launch_bounds__(256) void rope_perm(const bf16* __restrict__ in, int ldin,
                                                 bf16* __restrict__ out,
                                                 const int* __restrict__ pos_ids) {
  int idx = blockIdx.x * 256 + threadIdx.x;  // B*S*NH*64 threads
  int d = idx & 63;
  int h = (idx >> 6) & 31;
  int bs = idx >> 11;
  int b = bs >> 11, s = bs & 2047;
  float pos = (float)pos_ids[bs];
  float inv = exp2f(-(float)d * (13.287712379549449f / 64.0f));
  float fr = pos * inv, sn, cs;
  sincosf(fr, &sn, &cs);
  long bi = (long)bs * ldin + h * 128 + d;
  long bo = ((long)(b * 32 + h) * 2048 + s) * 128 + d;
  float x1 = __bfloat162float(in[bi]);
  float x2 = __bfloat162float(in[bi + 64]);
  out[bo] = __float2bfloat16(x1 * cs - x2 * sn);
  out[bo + 64] = __float2bfloat16(x2 * cs + x1 * sn);
}

// -------- transpose v_lat (b,s,2048 @ldv) -> tiled Vt: (b,g,kt) blocks of (256x32) --
__global__ __launch_bounds__(256) void transpose_kernel(const bf16* __restrict__ v,
                                                        int ldv,
                                                        bf16* __restrict__ vt) {
  __shared__ bf16 tile[32][33];
  int b = blockIdx.z;
  int c0 = blockIdx.x * 32;  // column in 2048 (= g*256 + d)
  int r0 = blockIdx.y * 32;  // row (s)
  int tx = threadIdx.x & 31, ty = threadIdx.x >> 5;
#pragma unroll
  for (int p = 0; p < 4; ++p) {
    int r = ty + p * 8;
    tile[r][tx] = v[((long)b * 2048 + r0 + r) * ldv + c0 + tx];
  }
  __syncthreads();
#pragma unroll
  for (int p = 0; p < 4; ++p) {
    int cidx = ty + p * 8;
    int cg = c0 + cidx;          // global column = g*256 + d
    int g = cg >> 8, d = cg & 255;
    int s = r0 + tx;
    vt[((long)((b * 8 + g) * 64 + (s >> 5))) * 8192 + d * 32 + (s & 31)] = tile[tx][cidx];
  }
}

// ---------------- flash attention v5: barrier-free, direct L2/L3 streaming --------
__global__ __launch_bounds__(512, 2) void attn_kernel(const bf16* __restrict__ Q,
                                                      const bf16* __restrict__ Kg,
                                                      const bf16* __restrict__ Vt,
                                                      bf16* __restrict__ fused) {
  __shared__ alignas(16) bf16 smem[32768];  // P: w*1024 (first 16KB); EP: w*4096
  const int t = threadIdx.x, w = t >> 6, l = t & 63;
  const int lane_r = l & 15, quad = l >> 4;
  // balanced 1-D decode: CU pairs sum to constant work (long blocks first)
  const int L = blockIdx.x;
  const int half = L >> 8, pair = L & 255;
  const int hb = pair >> 2, slot = pair & 3;
  const int qt = half ? slot : (7 - slot);
  const int b = hb >> 5, h = hb & 31;
  const int g = h >> 2, j = h & 3;
  const int q0 = qt * 256;
  const int qr0 = q0 + w * 32;
  const float scale = 0.08838834764831845f;  // 1/sqrt(128)

  const bf16* qbase = Q + ((long)(b * 32 + h) * 2048 + qr0 + lane_r) * 128 + quad * 8;
  bf16x8 qf[2][4];
#pragma unroll
  for (int m = 0; m < 2; ++m)
#pragma unroll
    for (int kd = 0; kd < 4; ++kd)
      qf[m][kd] = *(const bf16x8*)(qbase + m * 2048 + kd * 32);

  f32x4 acc[2][16] = {};
  float m_i[2][4], l_i[2][4];
#pragma unroll
  for (int m = 0; m < 2; ++m)
#pragma unroll
    for (int r = 0; r < 4; ++r) { m_i[m][r] = -1e30f; l_i[m][r] = 0.f; }

  const bf16* Kf = Kg + (long)(b * 32 + h) * 262144 + lane_r * 128 + quad * 8;
  const bf16* Vf = Vt + (long)(b * 8 + g) * 524288 + lane_r * 32 + quad * 8;
  bf16* Pw = smem + w * 1024;  // 32 rows x 32 cols, wave-private
  const int pslot = quad ^ ((lane_r >> 1) & 3);
  int poff0[4], poff1[4];
  {
    const int hi = lane_r >> 3, lo = lane_r & 7;
#pragma unroll
    for (int r = 0; r < 4; ++r) {
      int rq = quad * 4 + r;
      int sw = (rq >> 1) & 3;
      poff0[r] = rq * 32 + ((hi ^ sw) << 3) + lo;
      poff1[r] = rq * 32 + (((2 + hi) ^ sw) << 3) + lo;
    }
  }

  const int nkw = (qr0 >> 5) + 1;  // wave-private tile count (last tile = diagonal)
  for (int kt = 0; kt < nkw; ++kt) {
    const int k0 = kt * 32;
    const bool diag = (kt == nkw - 1);
    const bf16* Kt_ = Kf + (long)k0 * 128;
    const bf16* Vt_ = Vf + (long)kt * 8192;

    f32x4 s[2][2] = {};
#pragma unroll
    for (int ks = 0; ks < 2; ++ks) {
      bf16x8 kf[4];
#pragma unroll
      for (int kd = 0; kd < 4; ++kd)
        kf[kd] = *(const bf16x8*)(Kt_ + ks * 2048 + kd * 32);
#pragma unroll
      for (int kd = 0; kd < 4; ++kd) {
        s[0][ks] = MFMA16(qf[0][kd], kf[kd], s[0][ks]);
        s[1][ks] = MFMA16(qf[1][kd], kf[kd], s[1][ks]);
      }
    }
    float sc[2][2][4];
    if (diag) {
#pragma unroll
      for (int m = 0; m < 2; ++m) {
        const int qrowb = qr0 + m * 16 + quad * 4;
#pragma unroll
        for (int r = 0; r < 4; ++r) {
          sc[m][0][r] = (k0 + lane_r <= qrowb + r) ? s[m][0][r] * scale : -1e30f;
          sc[m][1][r] = (k0 + 16 + lane_r <= qrowb + r) ? s[m][1][r] * scale : -1e30f;
        }
      }
    } else {
#pragma unroll
      for (int m = 0; m < 2; ++m)
#pragma unroll
        for (int r = 0; r < 4; ++r) {
          sc[m][0][r] = s[m][0][r] * scale;
          sc[m][1][r] = s[m][1][r] * scale;
        }
    }

#pragma unroll
    for (int m = 0; m < 2; ++m) {
      float mx[4];
      bool grow = false;
#pragma unroll
      for (int r = 0; r < 4; ++r) {
        float v = fmaxf(sc[m][0][r], sc[m][1][r]);
#pragma unroll
        for (int o = 1; o < 16; o <<= 1) v = fmaxf(v, __shfl_xor(v, o));
        mx[r] = v;
        grow = grow || (v > m_i[m][r]);
      }
      if (__any((int)grow)) {
#pragma unroll
        for (int r = 0; r < 4; ++r) {
          float mnew = fmaxf(m_i[m][r], mx[r]);
          float alpha = __expf(m_i[m][r] - mnew);
          m_i[m][r] = mnew;
          l_i[m][r] *= alpha;
#pragma unroll
          for (int nt = 0; nt < 16; ++nt) acc[m][nt][r] *= alpha;
        }
      }
#pragma unroll
      for (int r = 0; r < 4; ++r) {
        float p0 = __expf(sc[m][0][r] - m_i[m][r]);
        float p1 = __expf(sc[m][1][r] - m_i[m][r]);
        float rs = p0 + p1;
#pragma unroll
        for (int o = 1; o < 16; o <<= 1) rs += __shfl_xor(rs, o);
        l_i[m][r] += rs;
        Pw[m * 512 + poff0[r]] = __float2bfloat16(p0);
        Pw[m * 512 + poff1[r]] = __float2bfloat16(p1);
      }
    }

    bf16x8 pf0 = *(const bf16x8*)&Pw[lane_r * 32 + pslot * 8];
    bf16x8 pf1 = *(const bf16x8*)&Pw[(16 + lane_r) * 32 + pslot * 8];
    __builtin_amdgcn_s_setprio(1);
#pragma unroll
    for (int nt = 0; nt < 16; ++nt) {
      bf16x8 vf = *(const bf16x8*)(Vt_ + nt * 512);
      acc[0][nt] = MFMA16(pf0, vf, acc[0][nt]);
      acc[1][nt] = MFMA16(pf1, vf, acc[1][nt]);
    }
    __builtin_amdgcn_s_setprio(0);
  }

  __syncthreads();  // all waves done with P before smem reuse
  bf16* EP = smem + w * 4096;  // 16 rows x 256 cols per wave (reused per m)
#pragma unroll
  for (int m = 0; m < 2; ++m) {
#pragma unroll
    for (int r = 0; r < 4; ++r) {
      float inv = 1.0f / l_i[m][r];
#pragma unroll
      for (int nt = 0; nt < 16; ++nt)
        EP[(quad * 4 + r) * 256 + nt * 16 + lane_r] = __float2bfloat16(acc[m][nt][r] * inv);
    }
#pragma unroll
    for (int op = 0; op < 8; ++op) {
      int row = op * 2 + (l >> 5);
      int qrow = qr0 + m * 16 + row;
      int sOut = j * 512 + (qrow >> 2), fi = qrow & 3;
      bf16x8 vread = *(const bf16x8*)&EP[row * 256 + (l & 31) * 8];
      *(bf16x8*)(fused + ((long)(b * 2048 + sOut)) * 8192 + fi * 2048 + g * 256 +
                 (l & 31) * 8) = vread;
    }
  }
}

// ---------------- launch ----------------
extern "C" void kernel_launch(void* const* d_in, const int* in_sizes, int n_in,
                              void* d_out, int out_size, void* d_ws, size_t ws_size,
                              hipStream_t stream) {
  const float* hidden = (const float*)d_in[0];
  const int* pos_ids = (const int*)d_in[2];
  const float* Wq = (const float*)d_in[3];
  const float* WVT = (const float*)d_in[4];
  const float* U = (const float*)d_in[5];
  const float* Wv = (const float*)d_in[6];
  const float* Wo = (const float*)d_in[7];
  float* out = (float*)d_out;

  bf16* ws = (bf16*)d_ws;
  bf16* WB = ws;                    // 33554432 elems (W3 stack; later Wo)
  bf16* UB = WB + 33554432;         // 1048576
  bf16* hidB = UB + 1048576;        // 16777216  (later reused as Qh)
  bf16* proj = hidB + 16777216;     // 33554432  (Q | k_lat | v_lat, ldc 8192; later Kh)
  bf16* Kb = proj + 33554432;       // 16777216
  bf16* vtB = Kb + 16777216;        // 8388608   (tiled Vt)
  bf16* fusedB = vtB + 8388608;     // 33554432
  bf16* Qh = hidB;
  bf16* Kh = proj;

  static bool attr_set = false;
  if (!attr_set) {
    hipFuncSetAttribute((const void*)gemm256<bf16>,
                        hipFuncAttributeMaxDynamicSharedMemorySize, 98304);
    hipFuncSetAttribute((const void*)gemm256<float>,
                        hipFuncAttributeMaxDynamicSharedMemorySize, 98304);
    attr_set = true;
  }

  cvt_f2b<<<16384, 256, 0, stream>>>(hidden, hidB, 4194304);
  cvt_f2b<<<16384, 256, 0, stream>>>(Wq, WB, 4194304);                // rows 0-4095
  cvt_f2b<<<8192, 256, 0, stream>>>(WVT, WB + 16777216, 2097152);     // rows 4096-6143
  cvt_f2b<<<8192, 256, 0, stream>>>(Wv, WB + 25165824, 2097152);      // rows 6144-8191
  // fused QKV projection: (4096x4096) . (8192x4096)^T -> proj (4096x8192)
  gemm256<bf16><<<dim3(32, 16), 512, 98304, stream>>>(hidB, WB, proj, 4096, 4096,
                                                      4096, 8192);
  cvt_f2b<<<1024, 256, 0, stream>>>(U, UB, 262144);
  // K reconstruction: klat cols of proj (offset 4096, lda 8192), batched over G
  gemm_bt<bf16><<<dim3(4, 32, 8), 256, 0, stream>>>(proj + 4096, UB, Kb, 4096, 512,
                                                    256, 8192, 2048, 4096, 256, 256,
                                                    512);
  transpose_kernel<<<dim3(64, 64, 2), 256, 0, stream>>>(proj + 6144, 8192, vtB);
  rope_perm<<<32768, 256, 0, stream>>>(proj, 8192, Qh, pos_ids);   // frees proj
  rope_perm<<<32768, 256, 0, stream>>>(Kb, 4096, Kh, pos_ids);     // Kh = proj region
  cvt_f2b<<<32768, 256, 0, stream>>>(Wo, WB, 8388608);
  attn_kernel<<<dim3(512, 1, 1), 512, 0, stream>>>(Qh, Kh, vtB, fusedB);
  gemm256<float><<<dim3(16, 16), 512, 98304, stream>>>(fusedB, WB, out, 8192, 8192,
                                                       8192, 4096);
}

// Round 4
// 1192.532 us; speedup vs baseline: 1.7269x; 1.1596x over previous
//
#include <hip/hip_runtime.h>
#include <hip/hip_bf16.h>

// B=2, S=2048, HID=4096, NH=32, D=128, G=8, GS=4, RK=256, FGD=256, FH=8192
typedef __hip_bfloat16 bf16;
typedef __bf16 bf16x8 __attribute__((ext_vector_type(8)));
typedef float f32x4 __attribute__((ext_vector_type(4)));

#define MFMA16(a, b, c) __builtin_amdgcn_mfma_f32_16x16x32_bf16(a, b, c, 0, 0, 0)

__device__ __forceinline__ void llds16(const bf16* g, bf16* lds) {
  __builtin_amdgcn_global_load_lds(
      (const __attribute__((address_space(1))) unsigned int*)g,
      (__attribute__((address_space(3))) unsigned int*)lds, 16, 0, 0);
}

__device__ __forceinline__ void storeC(float* p, float v) { *p = v; }
__device__ __forceinline__ void storeC(bf16* p, float v) { *p = __float2bfloat16(v); }

// ---------------- fp32 -> bf16 convert (vectorized) ----------------
__global__ __launch_bounds__(256) void cvt_f2b(const float* __restrict__ in,
                                               bf16* __restrict__ out, int n4) {
  int i = blockIdx.x * 256 + threadIdx.x;
  if (i >= n4) return;
  float4 v = ((const float4*)in)[i];
  union { bf16 h[4]; short4 s; } u;
  u.h[0] = __float2bfloat16(v.x);
  u.h[1] = __float2bfloat16(v.y);
  u.h[2] = __float2bfloat16(v.z);
  u.h[3] = __float2bfloat16(v.w);
  ((short4*)out)[i] = u.s;
}

// ------- 256x256-tile pipelined bf16 GEMM: C = A(MxK,lda) . B(NxK,ldb)^T ----------
// 512 threads = 8 waves (2M x 4N), per-wave 128x64 output. BK=32.
// 3-slot LDS ring (96 KB dynamic), staged 2 K-tiles ahead via global_load_lds;
// steady-state s_waitcnt vmcnt(8) (never drains in-loop). Chunk-XOR swizzle
// (slot = chunk ^ (row&3)) applied on stage-SOURCE and read (both-sides rule).
// Requires M%256==0, N%256==0, K%32==0, K>=96.
template <typename OUT_T>
__global__ __launch_bounds__(512, 2) void gemm256(
    const bf16* __restrict__ A, const bf16* __restrict__ B, OUT_T* __restrict__ C,
    int K, int lda, int ldb, int ldc) {
  extern __shared__ bf16 sm[];  // 3 slots x (A 8192 + B 8192) elems
  const int t = threadIdx.x, w = t >> 6, l = t & 63;
  const int lane_r = l & 15, quad = l >> 4;
  const int wm = (w >> 2) * 128, wn = (w & 3) * 64;
  const long m0 = (long)blockIdx.y * 256, n0 = (long)blockIdx.x * 256;
  const int r0 = t >> 2;
  const int c0 = (((t & 3) ^ (r0 & 3)) << 3);
  const bf16* As0 = A + (m0 + r0) * lda + c0;
  const bf16* As1 = A + (m0 + r0 + 128) * lda + c0;
  const bf16* Bs0 = B + (n0 + r0) * ldb + c0;
  const bf16* Bs1 = B + (n0 + r0 + 128) * ldb + c0;

#define STAGE(sl, kt)                                   \
  do {                                                  \
    long ko = (long)(kt) * 32;                          \
    bf16* dA = sm + (sl) * 16384;                       \
    bf16* dB = dA + 8192;                               \
    llds16(As0 + ko, dA + t * 8);                       \
    llds16(As1 + ko, dA + (t + 512) * 8);               \
    llds16(Bs0 + ko, dB + t * 8);                       \
    llds16(Bs1 + ko, dB + (t + 512) * 8);               \
  } while (0)

  f32x4 acc[8][4] = {};  // 128 VGPRs
  const int KT = K >> 5;
  const int sw = quad ^ (lane_r & 3);

  STAGE(0, 0);
  STAGE(1, 1);
  int sl = 0;
  for (int kt = 0; kt < KT; ++kt) {
    const int pre = KT - 1 - kt;
    if (pre >= 2) {
      int sl2 = sl + 2;
      if (sl2 >= 3) sl2 -= 3;
      STAGE(sl2, kt + 2);
      asm volatile("s_waitcnt vmcnt(8)" ::: "memory");
    } else if (pre == 1) {
      asm volatile("s_waitcnt vmcnt(4)" ::: "memory");
    } else {
      asm volatile("s_waitcnt vmcnt(0)" ::: "memory");
    }
    __builtin_amdgcn_s_barrier();
    __builtin_amdgcn_sched_barrier(0);
    const bf16* Al = sm + sl * 16384;
    const bf16* Bl = Al + 8192;
    bf16x8 af[8], bfr[4];
#pragma unroll
    for (int mt = 0; mt < 8; ++mt)
      af[mt] = *(const bf16x8*)&Al[(wm + mt * 16 + lane_r) * 32 + sw * 8];
#pragma unroll
    for (int nt = 0; nt < 4; ++nt)
      bfr[nt] = *(const bf16x8*)&Bl[(wn + nt * 16 + lane_r) * 32 + sw * 8];
    __builtin_amdgcn_s_setprio(1);
#pragma unroll
    for (int mt = 0; mt < 8; ++mt)
#pragma unroll
      for (int nt = 0; nt < 4; ++nt)
        acc[mt][nt] = MFMA16(af[mt], bfr[nt], acc[mt][nt]);
    __builtin_amdgcn_s_setprio(0);
    __builtin_amdgcn_s_barrier();
    if (++sl == 3) sl = 0;
  }
#undef STAGE

#pragma unroll
  for (int mt = 0; mt < 8; ++mt)
#pragma unroll
    for (int nt = 0; nt < 4; ++nt) {
      long row = m0 + wm + mt * 16 + quad * 4;
      long col = n0 + wn + nt * 16 + lane_r;
#pragma unroll
      for (int r = 0; r < 4; ++r) storeC(&C[(row + r) * ldc + col], acc[mt][nt][r]);
    }
}

// ---------------- generic bf16 GEMM: C = A(MxK,lda) . B(NxK,ldb)^T ----------------
template <typename OUT_T>
__global__ __launch_bounds__(256) void gemm_bt(
    const bf16* __restrict__ A, const bf16* __restrict__ B, OUT_T* __restrict__ C,
    int M, int N, int K, int lda, int ldb, int ldc,
    long batchA, long batchB, long batchC) {
  __shared__ alignas(16) bf16 As[128 * 32];
  __shared__ alignas(16) bf16 Bs[128 * 32];
  const int t = threadIdx.x;
  const int w = t >> 6, l = t & 63;
  const int lane_r = l & 15, quad = l >> 4;
  const int wm = (w >> 1) * 64, wn = (w & 1) * 64;
  const long m0 = (long)blockIdx.y * 128, n0 = (long)blockIdx.x * 128;
  A += (long)blockIdx.z * batchA;
  B += (long)blockIdx.z * batchB;
  C += (long)blockIdx.z * batchC;
  const int r0a = t >> 2;
  const int cba = (t & 3) * 8;
  f32x4 acc[4][4] = {};
  for (int k0 = 0; k0 < K; k0 += 32) {
    llds16(A + (m0 + r0a) * lda + k0 + cba, &As[t * 8]);
    llds16(A + (m0 + r0a + 64) * lda + k0 + cba, &As[(t + 256) * 8]);
    llds16(B + (n0 + r0a) * ldb + k0 + cba, &Bs[t * 8]);
    llds16(B + (n0 + r0a + 64) * ldb + k0 + cba, &Bs[(t + 256) * 8]);
    __syncthreads();
    bf16x8 af[4], bfr[4];
#pragma unroll
    for (int mt = 0; mt < 4; ++mt)
      af[mt] = *(const bf16x8*)&As[(wm + mt * 16 + lane_r) * 32 + quad * 8];
#pragma unroll
    for (int nt = 0; nt < 4; ++nt)
      bfr[nt] = *(const bf16x8*)&Bs[(wn + nt * 16 + lane_r) * 32 + quad * 8];
#pragma unroll
    for (int mt = 0; mt < 4; ++mt)
#pragma unroll
      for (int nt = 0; nt < 4; ++nt)
        acc[mt][nt] = MFMA16(af[mt], bfr[nt], acc[mt][nt]);
    __syncthreads();
  }
#pragma unroll
  for (int mt = 0; mt < 4; ++mt)
#pragma unroll
    for (int nt = 0; nt < 4; ++nt) {
      long row = m0 + wm + mt * 16 + quad * 4;
      long col = n0 + wn + nt * 16 + lane_r;
#pragma unroll
      for (int r = 0; r < 4; ++r) storeC(&C[(row + r) * ldc + col], acc[mt][nt][r]);
    }
}

// ------- RoPE + layout permute: (B,S,NH*128 @ldin) -> (B,NH,S,128), out-of-place ---
__global__ __launch_bounds__(256) void rope_perm(const bf16* __restrict__ in, int ldin,
                                                 bf16* __restrict__ out,
                                                 const int* __restrict__ pos_ids) {
  int idx = blockIdx.x * 256 + threadIdx.x;  // B*S*NH*64 threads
  int d = idx & 63;
  int h = (idx >> 6) & 31;
  int bs = idx >> 11;
  int b = bs >> 11, s = bs & 2047;
  float pos = (float)pos_ids[bs];
  float inv = exp2f(-(float)d * (13.287712379549449f / 64.0f));
  float fr = pos * inv, sn, cs;
  sincosf(fr, &sn, &cs);
  long bi = (long)bs * ldin + h * 128 + d;
  long bo = ((long)(b * 32 + h) * 2048 + s) * 128 + d;
  float x1 = __bfloat162float(in[bi]);
  float x2 = __bfloat162float(in[bi + 64]);
  out[bo] = __float2bfloat16(x1 * cs - x2 * sn);
  out[bo + 64] = __float2bfloat16(x2 * cs + x1 * sn);
}

// -------- transpose v_lat (b,s,2048 @ldv) -> tiled Vt: (b,g,kt) blocks of (256x32) --
__global__ __launch_bounds__(256) void transpose_kernel(const bf16* __restrict__ v,
                                                        int ldv,
                                                        bf16* __restrict__ vt) {
  __shared__ bf16 tile[32][33];
  int b = blockIdx.z;
  int c0 = blockIdx.x * 32;  // column in 2048 (= g*256 + d)
  int r0 = blockIdx.y * 32;  // row (s)
  int tx = threadIdx.x & 31, ty = threadIdx.x >> 5;
#pragma unroll
  for (int p = 0; p < 4; ++p) {
    int r = ty + p * 8;
    tile[r][tx] = v[((long)b * 2048 + r0 + r) * ldv + c0 + tx];
  }
  __syncthreads();
#pragma unroll
  for (int p = 0; p < 4; ++p) {
    int cidx = ty + p * 8;
    int cg = c0 + cidx;          // global column = g*256 + d
    int g = cg >> 8, d = cg & 255;
    int s = r0 + tx;
    vt[((long)((b * 8 + g) * 64 + (s >> 5))) * 8192 + d * 32 + (s & 31)] = tile[tx][cidx];
  }
}

// ------- flash attention v6: block-cooperative staged K/V, ring-2 counted vmcnt ----
// Balanced 1-D grid of 512 blocks (pairing decode as v5). 8 waves, QBLK=256,
// KVBLK=32; uniform block trip nk = qt*8+8. Ring-2 LDS double buffer staged 1
// tile ahead via global_load_lds (3 loads/thread/iter), steady-state
// s_waitcnt vmcnt(3) (never drains mid-loop). K/V staged ONCE per block and
// reused by 8 waves (8x less global traffic than v5's per-wave streams).
// LDS (elems): K[2] @0 (2x4096) | V[2] @8192 (2x8192) | P @24576 (8192).
__global__ __launch_bounds__(512, 2) void attn_kernel(const bf16* __restrict__ Q,
                                                      const bf16* __restrict__ Kg,
                                                      const bf16* __restrict__ Vt,
                                                      bf16* __restrict__ fused) {
  __shared__ alignas(16) bf16 smem[32768];  // 64 KB
  const int t = threadIdx.x, w = t >> 6, l = t & 63;
  const int lane_r = l & 15, quad = l >> 4;
  // balanced 1-D decode: CU pairs sum to constant work (long blocks first)
  const int L = blockIdx.x;
  const int half = L >> 8, pair = L & 255;
  const int hb = pair >> 2, slot = pair & 3;
  const int qt = half ? slot : (7 - slot);
  const int b = hb >> 5, h = hb & 31;
  const int g = h >> 2, j = h & 3;
  const int q0 = qt * 256;
  const int qr0 = q0 + w * 32;
  const float scale = 0.08838834764831845f;  // 1/sqrt(128)

  // Q fragments: 2 m-tiles x 4 k-chunks (A-operand: m=lane&15, k=quad*8+jj)
  const bf16* qbase = Q + ((long)(b * 32 + h) * 2048 + qr0 + lane_r) * 128 + quad * 8;
  bf16x8 qf[2][4];
#pragma unroll
  for (int m = 0; m < 2; ++m)
#pragma unroll
    for (int kd = 0; kd < 4; ++kd)
      qf[m][kd] = *(const bf16x8*)(qbase + m * 2048 + kd * 32);

  f32x4 acc[2][16] = {};
  float m_i[2][4], l_i[2][4];
#pragma unroll
  for (int m = 0; m < 2; ++m)
#pragma unroll
    for (int r = 0; r < 4; ++r) { m_i[m][r] = -1e30f; l_i[m][r] = 0.f; }

  // staging sources. K tile 32x128 (512 chunks): chunk s -> row s>>4, slot s&15
  // containing logical chunk (s&15)^(row&15). V tile 256x32 (1024 chunks):
  // chunk s -> row s>>2, slot s&3 containing logical chunk (s&3)^(row&3).
  const bf16* Kbase = Kg + (long)(b * 32 + h) * 262144;
  const bf16* Vtg = Vt + (long)(b * 8 + g) * 524288;
  const int kr = t >> 4, ck = (t & 15) ^ (kr & 15);
  const bf16* ksrc = Kbase + kr * 128 + ck * 8;
  const int vrA = t >> 2, cvA = (t & 3) ^ (vrA & 3);
  const int vrB = (t + 512) >> 2, cvB = ((t + 512) & 3) ^ (vrB & 3);
  const bf16* vsrcA = Vtg + vrA * 32 + cvA * 8;
  const bf16* vsrcB = Vtg + vrB * 32 + cvB * 8;

#define STAGE_T(buf, kt)                                                    \
  do {                                                                      \
    llds16(ksrc + (long)(kt) * 4096, &smem[(buf) * 4096 + t * 8]);          \
    llds16(vsrcA + (long)(kt) * 8192, &smem[8192 + (buf) * 8192 + t * 8]);  \
    llds16(vsrcB + (long)(kt) * 8192,                                       \
           &smem[8192 + (buf) * 8192 + (t + 512) * 8]);                     \
  } while (0)

  bf16* Pw = smem + 24576 + w * 1024;  // 32 rows x 32 cols, wave-private
  const int pslot = quad ^ ((lane_r >> 1) & 3);
  const int vslot = quad ^ (lane_r & 3);  // V read slot (row&3 == lane_r&3)
  int poff0[4], poff1[4];
  {
    const int hi = lane_r >> 3, lo = lane_r & 7;
#pragma unroll
    for (int r = 0; r < 4; ++r) {
      int rq = quad * 4 + r;
      int sw2 = (rq >> 1) & 3;
      poff0[r] = rq * 32 + ((hi ^ sw2) << 3) + lo;
      poff1[r] = rq * 32 + (((2 + hi) ^ sw2) << 3) + lo;
    }
  }

  const int nk = qt * 8 + 8;      // uniform block trip count
  const int kwmax = qt * 8 + w;   // last tile this wave computes (diagonal)

  STAGE_T(0, 0);
  for (int kt = 0; kt < nk; ++kt) {
    if (kt + 1 < nk) {
      STAGE_T((kt + 1) & 1, kt + 1);
      asm volatile("s_waitcnt vmcnt(3)" ::: "memory");  // prev stage landed
    } else {
      asm volatile("s_waitcnt vmcnt(0)" ::: "memory");
    }
    __builtin_amdgcn_s_barrier();
    __builtin_amdgcn_sched_barrier(0);
    const bf16* Ks = &smem[(kt & 1) * 4096];
    const bf16* Vs = &smem[8192 + (kt & 1) * 8192];

    if (kt <= kwmax) {
      const int k0 = kt * 32;
      const bool diag = (kt == kwmax);
      // ---- QK^T from staged K ----
      f32x4 s[2][2] = {};
#pragma unroll
      for (int ks = 0; ks < 2; ++ks) {
        bf16x8 kf[4];
#pragma unroll
        for (int kd = 0; kd < 4; ++kd) {
          int csw = (kd * 4 + quad) ^ lane_r;  // row&15 == lane_r
          kf[kd] = *(const bf16x8*)&Ks[(ks * 16 + lane_r) * 128 + csw * 8];
        }
#pragma unroll
        for (int kd = 0; kd < 4; ++kd) {
          s[0][ks] = MFMA16(qf[0][kd], kf[kd], s[0][ks]);
          s[1][ks] = MFMA16(qf[1][kd], kf[kd], s[1][ks]);
        }
      }
      float sc[2][2][4];
      if (diag) {
#pragma unroll
        for (int m = 0; m < 2; ++m) {
          const int qrowb = qr0 + m * 16 + quad * 4;
#pragma unroll
          for (int r = 0; r < 4; ++r) {
            sc[m][0][r] = (k0 + lane_r <= qrowb + r) ? s[m][0][r] * scale : -1e30f;
            sc[m][1][r] = (k0 + 16 + lane_r <= qrowb + r) ? s[m][1][r] * scale : -1e30f;
          }
        }
      } else {
#pragma unroll
        for (int m = 0; m < 2; ++m)
#pragma unroll
          for (int r = 0; r < 4; ++r) {
            sc[m][0][r] = s[m][0][r] * scale;
            sc[m][1][r] = s[m][1][r] * scale;
          }
      }

      // ---- online softmax (defer-rescale) ----
#pragma unroll
      for (int m = 0; m < 2; ++m) {
        float mx[4];
        bool grow = false;
#pragma unroll
        for (int r = 0; r < 4; ++r) {
          float v = fmaxf(sc[m][0][r], sc[m][1][r]);
#pragma unroll
          for (int o = 1; o < 16; o <<= 1) v = fmaxf(v, __shfl_xor(v, o));
          mx[r] = v;
          grow = grow || (v > m_i[m][r]);
        }
        if (__any((int)grow)) {
#pragma unroll
          for (int r = 0; r < 4; ++r) {
            float mnew = fmaxf(m_i[m][r], mx[r]);
            float alpha = __expf(m_i[m][r] - mnew);
            m_i[m][r] = mnew;
            l_i[m][r] *= alpha;
#pragma unroll
            for (int nt = 0; nt < 16; ++nt) acc[m][nt][r] *= alpha;
          }
        }
#pragma unroll
        for (int r = 0; r < 4; ++r) {
          float p0 = __expf(sc[m][0][r] - m_i[m][r]);
          float p1 = __expf(sc[m][1][r] - m_i[m][r]);
          float rs = p0 + p1;
#pragma unroll
          for (int o = 1; o < 16; o <<= 1) rs += __shfl_xor(rs, o);
          l_i[m][r] += rs;
          Pw[m * 512 + poff0[r]] = __float2bfloat16(p0);
          Pw[m * 512 + poff1[r]] = __float2bfloat16(p1);
        }
      }

      // ---- PV: P from wave-private LDS, V from staged LDS ----
      bf16x8 pf0 = *(const bf16x8*)&Pw[lane_r * 32 + pslot * 8];
      bf16x8 pf1 = *(const bf16x8*)&Pw[(16 + lane_r) * 32 + pslot * 8];
      __builtin_amdgcn_s_setprio(1);
#pragma unroll
      for (int nt = 0; nt < 16; ++nt) {
        bf16x8 vf = *(const bf16x8*)&Vs[(nt * 16 + lane_r) * 32 + vslot * 8];
        acc[0][nt] = MFMA16(pf0, vf, acc[0][nt]);
        acc[1][nt] = MFMA16(pf1, vf, acc[1][nt]);
      }
      __builtin_amdgcn_s_setprio(0);
    }
    __builtin_amdgcn_s_barrier();  // readers done before next iter's STAGE overwrite
  }
#undef STAGE_T

  // ---- epilogue: normalize, stage 16x256 per wave in LDS, coalesced 16B stores ----
  __syncthreads();  // all waves done with ring/P before smem reuse
  bf16* EP = smem + w * 4096;  // 16 rows x 256 cols per wave (reused per m)
#pragma unroll
  for (int m = 0; m < 2; ++m) {
#pragma unroll
    for (int r = 0; r < 4; ++r) {
      float inv = 1.0f / l_i[m][r];
#pragma unroll
      for (int nt = 0; nt < 16; ++nt)
        EP[(quad * 4 + r) * 256 + nt * 16 + lane_r] = __float2bfloat16(acc[m][nt][r] * inv);
    }
#pragma unroll
    for (int op = 0; op < 8; ++op) {
      int row = op * 2 + (l >> 5);
      int qrow = qr0 + m * 16 + row;
      int sOut = j * 512 + (qrow >> 2), fi = qrow & 3;
      bf16x8 vread = *(const bf16x8*)&EP[row * 256 + (l & 31) * 8];
      *(bf16x8*)(fused + ((long)(b * 2048 + sOut)) * 8192 + fi * 2048 + g * 256 +
                 (l & 31) * 8) = vread;
    }
  }
}

// ---------------- launch ----------------
extern "C" void kernel_launch(void* const* d_in, const int* in_sizes, int n_in,
                              void* d_out, int out_size, void* d_ws, size_t ws_size,
                              hipStream_t stream) {
  const float* hidden = (const float*)d_in[0];
  const int* pos_ids = (const int*)d_in[2];
  const float* Wq = (const float*)d_in[3];
  const float* WVT = (const float*)d_in[4];
  const float* U = (const float*)d_in[5];
  const float* Wv = (const float*)d_in[6];
  const float* Wo = (const float*)d_in[7];
  float* out = (float*)d_out;

  bf16* ws = (bf16*)d_ws;
  bf16* WB = ws;                    // 33554432 elems (W3 stack; later Wo)
  bf16* UB = WB + 33554432;         // 1048576
  bf16* hidB = UB + 1048576;        // 16777216  (later reused as Qh)
  bf16* proj = hidB + 16777216;     // 33554432  (Q | k_lat | v_lat, ldc 8192; later Kh)
  bf16* Kb = proj + 33554432;       // 16777216
  bf16* vtB = Kb + 16777216;        // 8388608   (tiled Vt)
  bf16* fusedB = vtB + 8388608;     // 33554432
  bf16* Qh = hidB;
  bf16* Kh = proj;

  static bool attr_set = false;
  if (!attr_set) {
    hipFuncSetAttribute((const void*)gemm256<bf16>,
                        hipFuncAttributeMaxDynamicSharedMemorySize, 98304);
    hipFuncSetAttribute((const void*)gemm256<float>,
                        hipFuncAttributeMaxDynamicSharedMemorySize, 98304);
    attr_set = true;
  }

  cvt_f2b<<<16384, 256, 0, stream>>>(hidden, hidB, 4194304);
  cvt_f2b<<<16384, 256, 0, stream>>>(Wq, WB, 4194304);                // rows 0-4095
  cvt_f2b<<<8192, 256, 0, stream>>>(WVT, WB + 16777216, 2097152);     // rows 4096-6143
  cvt_f2b<<<8192, 256, 0, stream>>>(Wv, WB + 25165824, 2097152);      // rows 6144-8191
  // fused QKV projection: (4096x4096) . (8192x4096)^T -> proj (4096x8192)
  gemm256<bf16><<<dim3(32, 16), 512, 98304, stream>>>(hidB, WB, proj, 4096, 4096,
                                                      4096, 8192);
  cvt_f2b<<<1024, 256, 0, stream>>>(U, UB, 262144);
  // K reconstruction: klat cols of proj (offset 4096, lda 8192), batched over G
  gemm_bt<bf16><<<dim3(4, 32, 8), 256, 0, stream>>>(proj + 4096, UB, Kb, 4096, 512,
                                                    256, 8192, 2048, 4096, 256, 256,
                                                    512);
  transpose_kernel<<<dim3(64, 64, 2), 256, 0, stream>>>(proj + 6144, 8192, vtB);
  rope_perm<<<32768, 256, 0, stream>>>(proj, 8192, Qh, pos_ids);   // frees proj
  rope_perm<<<32768, 256, 0, stream>>>(Kb, 4096, Kh, pos_ids);     // Kh = proj region
  cvt_f2b<<<32768, 256, 0, stream>>>(Wo, WB, 8388608);
  attn_kernel<<<dim3(512, 1, 1), 512, 0, stream>>>(Qh, Kh, vtB, fusedB);
  gemm256<float><<<dim3(16, 16), 512, 98304, stream>>>(fusedB, WB, out, 8192, 8192,
                                                       8192, 4096);
}

// Round 5
// 1161.902 us; speedup vs baseline: 1.7724x; 1.0264x over previous
//
#include <hip/hip_runtime.h>
#include <hip/hip_bf16.h>

// B=2, S=2048, HID=4096, NH=32, D=128, G=8, GS=4, RK=256, FGD=256, FH=8192
typedef __hip_bfloat16 bf16;
typedef __bf16 bf16x8 __attribute__((ext_vector_type(8)));
typedef float f32x4 __attribute__((ext_vector_type(4)));

#define MFMA16(a, b, c) __builtin_amdgcn_mfma_f32_16x16x32_bf16(a, b, c, 0, 0, 0)

__device__ __forceinline__ void llds16(const bf16* g, bf16* lds) {
  __builtin_amdgcn_global_load_lds(
      (const __attribute__((address_space(1))) unsigned int*)g,
      (__attribute__((address_space(3))) unsigned int*)lds, 16, 0, 0);
}

__device__ __forceinline__ void storeC(float* p, float v) { *p = v; }
__device__ __forceinline__ void storeC(bf16* p, float v) { *p = __float2bfloat16(v); }

// ---------------- fp32 -> bf16 convert (vectorized) ----------------
__global__ __launch_bounds__(256) void cvt_f2b(const float* __restrict__ in,
                                               bf16* __restrict__ out, int n4) {
  int i = blockIdx.x * 256 + threadIdx.x;
  if (i >= n4) return;
  float4 v = ((const float4*)in)[i];
  union { bf16 h[4]; short4 s; } u;
  u.h[0] = __float2bfloat16(v.x);
  u.h[1] = __float2bfloat16(v.y);
  u.h[2] = __float2bfloat16(v.z);
  u.h[3] = __float2bfloat16(v.w);
  ((short4*)out)[i] = u.s;
}

// ------- 256x256-tile 2-phase pipelined bf16 GEMM: C = A(MxK,lda) . B(NxK,ldb)^T ---
// 512 threads = 8 waves (2M x 4N), per-wave 128x64 output. BK=32.
// 3-slot LDS ring (96 KB dynamic). Per K-tile, TWO phases:
//   ph0: ds_read A(all mt)+B(nt01) | stage A(kt+2) | bar | lgkm0 | 16 MFMA | bar
//   ph1: ds_read B(nt23)           | stage B(kt+2) | vmcnt(4) | bar | lgkm0 | 16 MFMA | bar
// vmcnt(4) drains exactly tile kt+1's 4 loads, leaves kt+2's 4 in flight (never 0
// until the 2-tile tail). Bijective bank swizzle: slot = chunk ^ ((row>>1)&3) on
// BOTH stage-source and read -> 8 distinct 16B bank positions per 8 lanes.
// Requires M%256==0, N%256==0, K%32==0, K>=96.
template <typename OUT_T>
__global__ __launch_bounds__(512, 2) void gemm256(
    const bf16* __restrict__ A, const bf16* __restrict__ B, OUT_T* __restrict__ C,
    int K, int lda, int ldb, int ldc) {
  extern __shared__ bf16 sm[];  // 3 slots x (A 8192 + B 8192) elems
  const int t = threadIdx.x, w = t >> 6, l = t & 63;
  const int lane_r = l & 15, quad = l >> 4;
  const int wm = (w >> 2) * 128, wn = (w & 3) * 64;
  const long m0 = (long)blockIdx.y * 256, n0 = (long)blockIdx.x * 256;
  // staging: thread t owns chunks {t, t+512}; chunk s -> row s>>2, slot s&3,
  // slot must CONTAIN logical chunk (s&3) ^ ((row>>1)&3)  [row+128 preserves it]
  const int r0 = t >> 2;
  const int c0 = (((t & 3) ^ ((r0 >> 1) & 3)) << 3);
  const bf16* As0 = A + (m0 + r0) * lda + c0;
  const bf16* As1 = A + (m0 + r0 + 128) * lda + c0;
  const bf16* Bs0 = B + (n0 + r0) * ldb + c0;
  const bf16* Bs1 = B + (n0 + r0 + 128) * ldb + c0;

#define STAGE_A(sl_, kt_)                                \
  do {                                                   \
    long ko = (long)(kt_) * 32;                          \
    bf16* dA = sm + (sl_) * 16384;                       \
    llds16(As0 + ko, dA + t * 8);                        \
    llds16(As1 + ko, dA + (t + 512) * 8);                \
  } while (0)
#define STAGE_B(sl_, kt_)                                \
  do {                                                   \
    long ko = (long)(kt_) * 32;                          \
    bf16* dB = sm + (sl_) * 16384 + 8192;                \
    llds16(Bs0 + ko, dB + t * 8);                        \
    llds16(Bs1 + ko, dB + (t + 512) * 8);                \
  } while (0)

  f32x4 acc[8][4] = {};  // 128 VGPRs
  const int KT = K >> 5;
  const int sw = quad ^ ((lane_r >> 1) & 3);  // lane-constant read slot

  STAGE_A(0, 0);
  STAGE_B(0, 0);
  STAGE_A(1, 1);
  STAGE_B(1, 1);
  asm volatile("s_waitcnt vmcnt(4)" ::: "memory");  // tile 0 landed
  __builtin_amdgcn_s_barrier();

  int sl = 0;
  for (int kt = 0; kt < KT; ++kt) {
    const bf16* Al = sm + sl * 16384;
    const bf16* Bl = Al + 8192;
    int sl2 = sl + 2;
    if (sl2 >= 3) sl2 -= 3;
    const bool pf = (kt + 2 < KT);
    // ---- phase 0 ----
    bf16x8 af[8], bfr[2];
#pragma unroll
    for (int mt = 0; mt < 8; ++mt)
      af[mt] = *(const bf16x8*)&Al[(wm + mt * 16 + lane_r) * 32 + sw * 8];
#pragma unroll
    for (int nt = 0; nt < 2; ++nt)
      bfr[nt] = *(const bf16x8*)&Bl[(wn + nt * 16 + lane_r) * 32 + sw * 8];
    if (pf) STAGE_A(sl2, kt + 2);
    __builtin_amdgcn_sched_barrier(0);
    __builtin_amdgcn_s_barrier();
    asm volatile("s_waitcnt lgkmcnt(0)" ::: "memory");
    __builtin_amdgcn_sched_barrier(0);
    __builtin_amdgcn_s_setprio(1);
#pragma unroll
    for (int mt = 0; mt < 8; ++mt) {
      acc[mt][0] = MFMA16(af[mt], bfr[0], acc[mt][0]);
      acc[mt][1] = MFMA16(af[mt], bfr[1], acc[mt][1]);
    }
    __builtin_amdgcn_s_setprio(0);
    __builtin_amdgcn_s_barrier();
    // ---- phase 1 ----
    bf16x8 bfr2[2];
#pragma unroll
    for (int nt = 0; nt < 2; ++nt)
      bfr2[nt] = *(const bf16x8*)&Bl[(wn + (nt + 2) * 16 + lane_r) * 32 + sw * 8];
    if (pf) {
      STAGE_B(sl2, kt + 2);
      asm volatile("s_waitcnt vmcnt(4)" ::: "memory");
    } else {
      asm volatile("s_waitcnt vmcnt(0)" ::: "memory");
    }
    __builtin_amdgcn_sched_barrier(0);
    __builtin_amdgcn_s_barrier();
    asm volatile("s_waitcnt lgkmcnt(0)" ::: "memory");
    __builtin_amdgcn_sched_barrier(0);
    __builtin_amdgcn_s_setprio(1);
#pragma unroll
    for (int mt = 0; mt < 8; ++mt) {
      acc[mt][2] = MFMA16(af[mt], bfr2[0], acc[mt][2]);
      acc[mt][3] = MFMA16(af[mt], bfr2[1], acc[mt][3]);
    }
    __builtin_amdgcn_s_setprio(0);
    __builtin_amdgcn_s_barrier();
    if (++sl == 3) sl = 0;
  }
#undef STAGE_A
#undef STAGE_B

#pragma unroll
  for (int mt = 0; mt < 8; ++mt)
#pragma unroll
    for (int nt = 0; nt < 4; ++nt) {
      long row = m0 + wm + mt * 16 + quad * 4;
      long col = n0 + wn + nt * 16 + lane_r;
#pragma unroll
      for (int r = 0; r < 4; ++r) storeC(&C[(row + r) * ldc + col], acc[mt][nt][r]);
    }
}

// ---------------- generic bf16 GEMM: C = A(MxK,lda) . B(NxK,ldb)^T ----------------
template <typename OUT_T>
__global__ __launch_bounds__(256) void gemm_bt(
    const bf16* __restrict__ A, const bf16* __restrict__ B, OUT_T* __restrict__ C,
    int M, int N, int K, int lda, int ldb, int ldc,
    long batchA, long batchB, long batchC) {
  __shared__ alignas(16) bf16 As[128 * 32];
  __shared__ alignas(16) bf16 Bs[128 * 32];
  const int t = threadIdx.x;
  const int w = t >> 6, l = t & 63;
  const int lane_r = l & 15, quad = l >> 4;
  const int wm = (w >> 1) * 64, wn = (w & 1) * 64;
  const long m0 = (long)blockIdx.y * 128, n0 = (long)blockIdx.x * 128;
  A += (long)blockIdx.z * batchA;
  B += (long)blockIdx.z * batchB;
  C += (long)blockIdx.z * batchC;
  const int r0a = t >> 2;
  const int cba = (t & 3) * 8;
  f32x4 acc[4][4] = {};
  for (int k0 = 0; k0 < K; k0 += 32) {
    llds16(A + (m0 + r0a) * lda + k0 + cba, &As[t * 8]);
    llds16(A + (m0 + r0a + 64) * lda + k0 + cba, &As[(t + 256) * 8]);
    llds16(B + (n0 + r0a) * ldb + k0 + cba, &Bs[t * 8]);
    llds16(B + (n0 + r0a + 64) * ldb + k0 + cba, &Bs[(t + 256) * 8]);
    __syncthreads();
    bf16x8 af[4], bfr[4];
#pragma unroll
    for (int mt = 0; mt < 4; ++mt)
      af[mt] = *(const bf16x8*)&As[(wm + mt * 16 + lane_r) * 32 + quad * 8];
#pragma unroll
    for (int nt = 0; nt < 4; ++nt)
      bfr[nt] = *(const bf16x8*)&Bs[(wn + nt * 16 + lane_r) * 32 + quad * 8];
#pragma unroll
    for (int mt = 0; mt < 4; ++mt)
#pragma unroll
      for (int nt = 0; nt < 4; ++nt)
        acc[mt][nt] = MFMA16(af[mt], bfr[nt], acc[mt][nt]);
    __syncthreads();
  }
#pragma unroll
  for (int mt = 0; mt < 4; ++mt)
#pragma unroll
    for (int nt = 0; nt < 4; ++nt) {
      long row = m0 + wm + mt * 16 + quad * 4;
      long col = n0 + wn + nt * 16 + lane_r;
#pragma unroll
      for (int r = 0; r < 4; ++r) storeC(&C[(row + r) * ldc + col], acc[mt][nt][r]);
    }
}

// ------- RoPE + layout permute: (B,S,NH*128 @ldin) -> (B,NH,S,128), out-of-place ---
__global__ __launch_bounds__(256) void rope_perm(const bf16* __restrict__ in, int ldin,
                                                 bf16* __restrict__ out,
                                                 const int* __restrict__ pos_ids) {
  int idx = blockIdx.x * 256 + threadIdx.x;  // B*S*NH*64 threads
  int d = idx & 63;
  int h = (idx >> 6) & 31;
  int bs = idx >> 11;
  int b = bs >> 11, s = bs & 2047;
  float pos = (float)pos_ids[bs];
  float inv = exp2f(-(float)d * (13.287712379549449f / 64.0f));
  float fr = pos * inv, sn, cs;
  sincosf(fr, &sn, &cs);
  long bi = (long)bs * ldin + h * 128 + d;
  long bo = ((long)(b * 32 + h) * 2048 + s) * 128 + d;
  float x1 = __bfloat162float(in[bi]);
  float x2 = __bfloat162float(in[bi + 64]);
  out[bo] = __float2bfloat16(x1 * cs - x2 * sn);
  out[bo + 64] = __float2bfloat16(x2 * cs + x1 * sn);
}

// -------- transpose v_lat (b,s,2048 @ldv) -> tiled Vt: (b,g,kt) blocks of (256x32) --
__global__ __launch_bounds__(256) void transpose_kernel(const bf16* __restrict__ v,
                                                        int ldv,
                                                        bf16* __restrict__ vt) {
  __shared__ bf16 tile[32][33];
  int b = blockIdx.z;
  int c0 = blockIdx.x * 32;  // column in 2048 (= g*256 + d)
  int r0 = blockIdx.y * 32;  // row (s)
  int tx = threadIdx.x & 31, ty = threadIdx.x >> 5;
#pragma unroll
  for (int p = 0; p < 4; ++p) {
    int r = ty + p * 8;
    tile[r][tx] = v[((long)b * 2048 + r0 + r) * ldv + c0 + tx];
  }
  __syncthreads();
#pragma unroll
  for (int p = 0; p < 4; ++p) {
    int cidx = ty + p * 8;
    int cg = c0 + cidx;          // global column = g*256 + d
    int g = cg >> 8, d = cg & 255;
    int s = r0 + tx;
    vt[((long)((b * 8 + g) * 64 + (s >> 5))) * 8192 + d * 32 + (s & 31)] = tile[tx][cidx];
  }
}

// ------- flash attention v6b: block-cooperative staged K/V, ring-2 counted vmcnt ---
// As v6, with the bijective V swizzle: slot = chunk ^ ((row>>1)&3) both sides.
__global__ __launch_bounds__(512, 2) void attn_kernel(const bf16* __restrict__ Q,
                                                      const bf16* __restrict__ Kg,
                                                      const bf16* __restrict__ Vt,
                                                      bf16* __restrict__ fused) {
  __shared__ alignas(16) bf16 smem[32768];  // 64 KB
  const int t = threadIdx.x, w = t >> 6, l = t & 63;
  const int lane_r = l & 15, quad = l >> 4;
  // balanced 1-D decode: CU pairs sum to constant work (long blocks first)
  const int L = blockIdx.x;
  const int half = L >> 8, pair = L & 255;
  const int hb = pair >> 2, slot = pair & 3;
  const int qt = half ? slot : (7 - slot);
  const int b = hb >> 5, h = hb & 31;
  const int g = h >> 2, j = h & 3;
  const int q0 = qt * 256;
  const int qr0 = q0 + w * 32;
  const float scale = 0.08838834764831845f;  // 1/sqrt(128)

  // Q fragments: 2 m-tiles x 4 k-chunks (A-operand: m=lane&15, k=quad*8+jj)
  const bf16* qbase = Q + ((long)(b * 32 + h) * 2048 + qr0 + lane_r) * 128 + quad * 8;
  bf16x8 qf[2][4];
#pragma unroll
  for (int m = 0; m < 2; ++m)
#pragma unroll
    for (int kd = 0; kd < 4; ++kd)
      qf[m][kd] = *(const bf16x8*)(qbase + m * 2048 + kd * 32);

  f32x4 acc[2][16] = {};
  float m_i[2][4], l_i[2][4];
#pragma unroll
  for (int m = 0; m < 2; ++m)
#pragma unroll
    for (int r = 0; r < 4; ++r) { m_i[m][r] = -1e30f; l_i[m][r] = 0.f; }

  // staging sources. K tile 32x128 (512 chunks): chunk s -> row s>>4, slot s&15
  // containing logical chunk (s&15)^(row&15). V tile 256x32 (1024 chunks):
  // chunk s -> row s>>2, slot s&3 containing logical chunk (s&3)^((row>>1)&3).
  const bf16* Kbase = Kg + (long)(b * 32 + h) * 262144;
  const bf16* Vtg = Vt + (long)(b * 8 + g) * 524288;
  const int kr = t >> 4, ck = (t & 15) ^ (kr & 15);
  const bf16* ksrc = Kbase + kr * 128 + ck * 8;
  const int vrA = t >> 2, cvA = (t & 3) ^ ((vrA >> 1) & 3);
  const int vrB = (t + 512) >> 2, cvB = (t & 3) ^ ((vrB >> 1) & 3);
  const bf16* vsrcA = Vtg + vrA * 32 + cvA * 8;
  const bf16* vsrcB = Vtg + vrB * 32 + cvB * 8;

#define STAGE_T(buf, kt)                                                    \
  do {                                                                      \
    llds16(ksrc + (long)(kt) * 4096, &smem[(buf) * 4096 + t * 8]);          \
    llds16(vsrcA + (long)(kt) * 8192, &smem[8192 + (buf) * 8192 + t * 8]);  \
    llds16(vsrcB + (long)(kt) * 8192,                                       \
           &smem[8192 + (buf) * 8192 + (t + 512) * 8]);                     \
  } while (0)

  bf16* Pw = smem + 24576 + w * 1024;  // 32 rows x 32 cols, wave-private
  const int pslot = quad ^ ((lane_r >> 1) & 3);
  const int vslot = quad ^ ((lane_r >> 1) & 3);  // V read slot (bijective swizzle)
  int poff0[4], poff1[4];
  {
    const int hi = lane_r >> 3, lo = lane_r & 7;
#pragma unroll
    for (int r = 0; r < 4; ++r) {
      int rq = quad * 4 + r;
      int sw2 = (rq >> 1) & 3;
      poff0[r] = rq * 32 + ((hi ^ sw2) << 3) + lo;
      poff1[r] = rq * 32 + (((2 + hi) ^ sw2) << 3) + lo;
    }
  }

  const int nk = qt * 8 + 8;      // uniform block trip count
  const int kwmax = qt * 8 + w;   // last tile this wave computes (diagonal)

  STAGE_T(0, 0);
  for (int kt = 0; kt < nk; ++kt) {
    if (kt + 1 < nk) {
      STAGE_T((kt + 1) & 1, kt + 1);
      asm volatile("s_waitcnt vmcnt(3)" ::: "memory");  // prev stage landed
    } else {
      asm volatile("s_waitcnt vmcnt(0)" ::: "memory");
    }
    __builtin_amdgcn_s_barrier();
    __builtin_amdgcn_sched_barrier(0);
    const bf16* Ks = &smem[(kt & 1) * 4096];
    const bf16* Vs = &smem[8192 + (kt & 1) * 8192];

    if (kt <= kwmax) {
      const int k0 = kt * 32;
      const bool diag = (kt == kwmax);
      // ---- QK^T from staged K ----
      f32x4 s[2][2] = {};
#pragma unroll
      for (int ks = 0; ks < 2; ++ks) {
        bf16x8 kf[4];
#pragma unroll
        for (int kd = 0; kd < 4; ++kd) {
          int csw = (kd * 4 + quad) ^ lane_r;  // row&15 == lane_r
          kf[kd] = *(const bf16x8*)&Ks[(ks * 16 + lane_r) * 128 + csw * 8];
        }
#pragma unroll
        for (int kd = 0; kd < 4; ++kd) {
          s[0][ks] = MFMA16(qf[0][kd], kf[kd], s[0][ks]);
          s[1][ks] = MFMA16(qf[1][kd], kf[kd], s[1][ks]);
        }
      }
      float sc[2][2][4];
      if (diag) {
#pragma unroll
        for (int m = 0; m < 2; ++m) {
          const int qrowb = qr0 + m * 16 + quad * 4;
#pragma unroll
          for (int r = 0; r < 4; ++r) {
            sc[m][0][r] = (k0 + lane_r <= qrowb + r) ? s[m][0][r] * scale : -1e30f;
            sc[m][1][r] = (k0 + 16 + lane_r <= qrowb + r) ? s[m][1][r] * scale : -1e30f;
          }
        }
      } else {
#pragma unroll
        for (int m = 0; m < 2; ++m)
#pragma unroll
          for (int r = 0; r < 4; ++r) {
            sc[m][0][r] = s[m][0][r] * scale;
            sc[m][1][r] = s[m][1][r] * scale;
          }
      }

      // ---- online softmax (defer-rescale) ----
#pragma unroll
      for (int m = 0; m < 2; ++m) {
        float mx[4];
        bool grow = false;
#pragma unroll
        for (int r = 0; r < 4; ++r) {
          float v = fmaxf(sc[m][0][r], sc[m][1][r]);
#pragma unroll
          for (int o = 1; o < 16; o <<= 1) v = fmaxf(v, __shfl_xor(v, o));
          mx[r] = v;
          grow = grow || (v > m_i[m][r]);
        }
        if (__any((int)grow)) {
#pragma unroll
          for (int r = 0; r < 4; ++r) {
            float mnew = fmaxf(m_i[m][r], mx[r]);
            float alpha = __expf(m_i[m][r] - mnew);
            m_i[m][r] = mnew;
            l_i[m][r] *= alpha;
#pragma unroll
            for (int nt = 0; nt < 16; ++nt) acc[m][nt][r] *= alpha;
          }
        }
#pragma unroll
        for (int r = 0; r < 4; ++r) {
          float p0 = __expf(sc[m][0][r] - m_i[m][r]);
          float p1 = __expf(sc[m][1][r] - m_i[m][r]);
          float rs = p0 + p1;
#pragma unroll
          for (int o = 1; o < 16; o <<= 1) rs += __shfl_xor(rs, o);
          l_i[m][r] += rs;
          Pw[m * 512 + poff0[r]] = __float2bfloat16(p0);
          Pw[m * 512 + poff1[r]] = __float2bfloat16(p1);
        }
      }

      // ---- PV: P from wave-private LDS, V from staged LDS ----
      bf16x8 pf0 = *(const bf16x8*)&Pw[lane_r * 32 + pslot * 8];
      bf16x8 pf1 = *(const bf16x8*)&Pw[(16 + lane_r) * 32 + pslot * 8];
      __builtin_amdgcn_s_setprio(1);
#pragma unroll
      for (int nt = 0; nt < 16; ++nt) {
        bf16x8 vf = *(const bf16x8*)&Vs[(nt * 16 + lane_r) * 32 + vslot * 8];
        acc[0][nt] = MFMA16(pf0, vf, acc[0][nt]);
        acc[1][nt] = MFMA16(pf1, vf, acc[1][nt]);
      }
      __builtin_amdgcn_s_setprio(0);
    }
    __builtin_amdgcn_s_barrier();  // readers done before next iter's STAGE overwrite
  }
#undef STAGE_T

  // ---- epilogue: normalize, stage 16x256 per wave in LDS, coalesced 16B stores ----
  __syncthreads();  // all waves done with ring/P before smem reuse
  bf16* EP = smem + w * 4096;  // 16 rows x 256 cols per wave (reused per m)
#pragma unroll
  for (int m = 0; m < 2; ++m) {
#pragma unroll
    for (int r = 0; r < 4; ++r) {
      float inv = 1.0f / l_i[m][r];
#pragma unroll
      for (int nt = 0; nt < 16; ++nt)
        EP[(quad * 4 + r) * 256 + nt * 16 + lane_r] = __float2bfloat16(acc[m][nt][r] * inv);
    }
#pragma unroll
    for (int op = 0; op < 8; ++op) {
      int row = op * 2 + (l >> 5);
      int qrow = qr0 + m * 16 + row;
      int sOut = j * 512 + (qrow >> 2), fi = qrow & 3;
      bf16x8 vread = *(const bf16x8*)&EP[row * 256 + (l & 31) * 8];
      *(bf16x8*)(fused + ((long)(b * 2048 + sOut)) * 8192 + fi * 2048 + g * 256 +
                 (l & 31) * 8) = vread;
    }
  }
}

// ---------------- launch ----------------
extern "C" void kernel_launch(void* const* d_in, const int* in_sizes, int n_in,
                              void* d_out, int out_size, void* d_ws, size_t ws_size,
                              hipStream_t stream) {
  const float* hidden = (const float*)d_in[0];
  const int* pos_ids = (const int*)d_in[2];
  const float* Wq = (const float*)d_in[3];
  const float* WVT = (const float*)d_in[4];
  const float* U = (const float*)d_in[5];
  const float* Wv = (const float*)d_in[6];
  const float* Wo = (const float*)d_in[7];
  float* out = (float*)d_out;

  bf16* ws = (bf16*)d_ws;
  bf16* WB = ws;                    // 33554432 elems (W3 stack; later Wo)
  bf16* UB = WB + 33554432;         // 1048576
  bf16* hidB = UB + 1048576;        // 16777216  (later reused as Qh)
  bf16* proj = hidB + 16777216;     // 33554432  (Q | k_lat | v_lat, ldc 8192; later Kh)
  bf16* Kb = proj + 33554432;       // 16777216
  bf16* vtB = Kb + 16777216;        // 8388608   (tiled Vt)
  bf16* fusedB = vtB + 8388608;     // 33554432
  bf16* Qh = hidB;
  bf16* Kh = proj;

  static bool attr_set = false;
  if (!attr_set) {
    hipFuncSetAttribute((const void*)gemm256<bf16>,
                        hipFuncAttributeMaxDynamicSharedMemorySize, 98304);
    hipFuncSetAttribute((const void*)gemm256<float>,
                        hipFuncAttributeMaxDynamicSharedMemorySize, 98304);
    attr_set = true;
  }

  cvt_f2b<<<16384, 256, 0, stream>>>(hidden, hidB, 4194304);
  cvt_f2b<<<16384, 256, 0, stream>>>(Wq, WB, 4194304);                // rows 0-4095
  cvt_f2b<<<8192, 256, 0, stream>>>(WVT, WB + 16777216, 2097152);     // rows 4096-6143
  cvt_f2b<<<8192, 256, 0, stream>>>(Wv, WB + 25165824, 2097152);      // rows 6144-8191
  // fused QKV projection: (4096x4096) . (8192x4096)^T -> proj (4096x8192)
  gemm256<bf16><<<dim3(32, 16), 512, 98304, stream>>>(hidB, WB, proj, 4096, 4096,
                                                      4096, 8192);
  cvt_f2b<<<1024, 256, 0, stream>>>(U, UB, 262144);
  // K reconstruction: klat cols of proj (offset 4096, lda 8192), batched over G
  gemm_bt<bf16><<<dim3(4, 32, 8), 256, 0, stream>>>(proj + 4096, UB, Kb, 4096, 512,
                                                    256, 8192, 2048, 4096, 256, 256,
                                                    512);
  transpose_kernel<<<dim3(64, 64, 2), 256, 0, stream>>>(proj + 6144, 8192, vtB);
  rope_perm<<<32768, 256, 0, stream>>>(proj, 8192, Qh, pos_ids);   // frees proj
  rope_perm<<<32768, 256, 0, stream>>>(Kb, 4096, Kh, pos_ids);     // Kh = proj region
  cvt_f2b<<<32768, 256, 0, stream>>>(Wo, WB, 8388608);
  attn_kernel<<<dim3(512, 1, 1), 512, 0, stream>>>(Qh, Kh, vtB, fusedB);
  gemm256<float><<<dim3(16, 16), 512, 98304, stream>>>(fusedB, WB, out, 8192, 8192,
                                                       8192, 4096);
}